// Round 9
// baseline (819.509 us; speedup 1.0000x reference)
//
#include <hip/hip_runtime.h>
#include <math.h>

#define N_EX 10000
#define N_KC 500
#define D 128
#define HID 128
#define BB 256
#define SS 500
#define NROWS 127744   // B*(S-1)

typedef float vf4 __attribute__((ext_vector_type(4)));
typedef _Float16 hf2 __attribute__((ext_vector_type(2)));

__device__ __forceinline__ float sigm(float x) { return 1.f / (1.f + __expf(-x)); }
__device__ __forceinline__ float tanh_fast(float x) { return 1.f - 2.f / (1.f + __expf(2.f * x)); }

__device__ __forceinline__ hf2 u2h(unsigned v) { union { unsigned u; hf2 h; } x; x.u = v; return x.h; }

// quad-lane sum via DPP quad_perm (VALU pipe, no LDS)
__device__ __forceinline__ float quad_sum(float x) {
    int a = __builtin_amdgcn_update_dpp(0, __float_as_int(x), 0xB1, 0xF, 0xF, true); // xor 1
    x += __int_as_float(a);
    int b = __builtin_amdgcn_update_dpp(0, __float_as_int(x), 0x4E, 0xF, 0xF, true); // xor 2
    x += __int_as_float(b);
    return x;
}

// ---------------- precompute: transposes + v1 + gbias4 + wlstm16(f16) + projC row 0 ----------------
// wlstm16 (f16): element e = i*4096 + t*8 + x, i in [0,16), t=thread in [0,512), x in [0,8).
// For t=u*4+q, i=g*4+j: value = (f16) w_hh[(g*128+u)*128 + q*32 + j*8 + x]
// Kernel loads uint4 #i at w16[i*512+t] -> 8 f16 = dims j*8..j*8+7 of gate-row g (q-segment).
// gbias4[u*4+g] = b_ih[g*128+u] + b_hh[g*128+u]; projC[0] = gbias4 (respond==0 row)
__global__ void k_precomp(const float* rd_w, const float* w_ih, const float* fc1_w,
                          const float* b_ih, const float* b_hh, const float* W1, const float* a_att,
                          const float* w_hh,
                          float* rd_wT, float* w_ihT0, float* w_ihT1,
                          float* fc1_AT, float* fc1_BT, float* gbias4, float* v1,
                          unsigned short* wlstm16, float* projC) {
    int idx = blockIdx.x * blockDim.x + threadIdx.x;
    int stride = gridDim.x * blockDim.x;
    const int N1 = 2 * 256 * 128;
    const int N2 = 128 * 512;
    const int N3 = 128 * 512;
    const int N4 = 128 * 128;
    const int N5 = 128 * 128;
    const int N6 = 512;
    const int N7 = 256;
    const int N8 = 65536;          // 16 uint4-slots * 512 threads * 8 f16
    int total = N1 + N2 + N3 + N4 + N5 + N6 + N7 + N8;
    for (int tt = idx; tt < total; tt += stride) {
        int u = tt;
        if (u < N1) {
            int h = u / (256 * 128); int rem = u % (256 * 128); int c = rem / 128; int dd = rem % 128;
            rd_wT[u] = rd_w[h * 128 * 256 + dd * 256 + c];
        } else if ((u -= N1) < N2) {
            int k = u / 512, g = u % 512; w_ihT0[u] = w_ih[g * 256 + k];
        } else if ((u -= N2) < N3) {
            int k = u / 512, g = u % 512; w_ihT1[u] = w_ih[g * 256 + 128 + k];
        } else if ((u -= N3) < N4) {
            int k = u / 128, j = u % 128; fc1_AT[u] = fc1_w[j * 256 + k];
        } else if ((u -= N4) < N5) {
            int k = u / 128, j = u % 128; fc1_BT[u] = fc1_w[j * 256 + 128 + k];
        } else if ((u -= N5) < N6) {
            int uu = u >> 2, g = u & 3;
            float v = b_ih[g * 128 + uu] + b_hh[g * 128 + uu];
            gbias4[u] = v;
            projC[u] = v;                 // respond==0 row
        } else if ((u -= N6) < N7) {
            int h = u / 128, k = u % 128;
            const float* wr = W1 + h * 16384 + k * 128;
            const float* av = a_att + h * 256;
            float acc = 0.f;
            for (int d = 0; d < 128; ++d) acc += wr[d] * av[d];
            v1[u] = acc;
        } else {
            u -= N7;
            int x = u & 7;
            int t = (u >> 3) & 511;
            int i = u >> 12;
            int g = i >> 2, j = i & 3;
            int uu = t >> 2, q = t & 3;
            float val = w_hh[(g * 128 + uu) * 128 + q * 32 + j * 8 + x];
            ((_Float16*)wlstm16)[u] = (_Float16)val;
        }
    }
}

// ---------------- kc_Wh + s_kc ----------------
__global__ void k_kc(const float* kc_embed, const float* W1, const float* a_att,
                     float* kc_Wh, float* s_kc) {
    int j = blockIdx.x, h = blockIdx.y, d = threadIdx.x;
    __shared__ float row[128];
    __shared__ float red[128];
    row[d] = kc_embed[j * 128 + d];
    __syncthreads();
    const float* w = W1 + h * 16384;
    float acc = 0.f;
    for (int k = 0; k < 128; ++k) acc += row[k] * w[k * 128 + d];
    kc_Wh[(h * 500 + j) * 128 + d] = acc;
    red[d] = acc * a_att[h * 256 + 128 + d];
    __syncthreads();
    for (int s = 64; s > 0; s >>= 1) { if (d < s) red[d] += red[d + s]; __syncthreads(); }
    if (d == 0) s_kc[h * 500 + j] = red[0];
}

// ---------------- s_ex[h][i] = ex_embed[i] . v1[h] ----------------
__global__ void k_sex(const float* ex_embed, const float* v1, float* s_ex) {
    int t = blockIdx.x * blockDim.x + threadIdx.x;
    if (t >= 2 * N_EX) return;
    int h = t / N_EX, i = t % N_EX;
    const float4* e4 = (const float4*)(ex_embed + (size_t)i * 128);
    const float4* v4 = (const float4*)(v1 + h * 128);
    float acc = 0.f;
    for (int k = 0; k < 32; ++k) {
        float4 a = e4[k], b = v4[k];
        acc += a.x * b.x + a.y * b.y + a.z * b.z + a.w * b.w;
    }
    s_ex[h * N_EX + i] = acc;
}

// ---------------- fused attention softmax + new_kc GEMV (8 rows / block) ----------------
__global__ __launch_bounds__(256) void k_attnk(const int* adj, const float* s_ex, const float* s_kc,
                                               const float* kc_Wh, float* new_kc) {
    int i0 = blockIdx.x * 8, h = blockIdx.y, t = threadIdx.x;
    __shared__ float a_lds[8 * 500];
    __shared__ float skc_l[500];
    for (int j = t; j < 500; j += 256) skc_l[j] = s_kc[h * 500 + j];
    __syncthreads();
    {
        int lg = t >> 5, lane = t & 31;
        int i = i0 + lg;
        float sex = s_ex[h * N_EX + i];
        const int* arow = adj + (size_t)i * 500;
        float* arow_l = a_lds + lg * 500;
        float lmax = -INFINITY;
        for (int j = lane; j < 500; j += 32) {
            float e = sex + skc_l[j];
            e = (e >= 0.f) ? e : 0.2f * e;
            e = (arow[j] > 0) ? e : -INFINITY;
            arow_l[j] = e;
            lmax = fmaxf(lmax, e);
        }
#pragma unroll
        for (int m = 16; m > 0; m >>= 1) lmax = fmaxf(lmax, __shfl_xor(lmax, m));
        float lsum = 0.f;
        for (int j = lane; j < 500; j += 32) {
            float w = __expf(arow_l[j] - lmax);
            arow_l[j] = w;
            lsum += w;
        }
#pragma unroll
        for (int m = 16; m > 0; m >>= 1) lsum += __shfl_xor(lsum, m);
        float inv = 1.f / lsum;
        for (int j = lane; j < 500; j += 32) arow_l[j] *= inv;
    }
    __syncthreads();
    int d = t & 127, half = t >> 7;
    const float* kcw = kc_Wh + h * 500 * 128;
    float acc[4] = {0.f, 0.f, 0.f, 0.f};
    for (int j = 0; j < 500; ++j) {
        float w = kcw[j * 128 + d];
#pragma unroll
        for (int r = 0; r < 4; ++r) acc[r] += a_lds[(half * 4 + r) * 500 + j] * w;
    }
#pragma unroll
    for (int r = 0; r < 4; ++r)
        new_kc[((size_t)h * N_EX + i0 + half * 4 + r) * 128 + d] = acc[r];
}

// ---------------- GAT tail: ex@E, readout, ELU   (8 rows / block) ----------------
__global__ void k_gat2(const float* new_kc, const float* ex_embed, const float* E,
                       const float* rd_wT, const float* rd_b, float* H) {
    int i0 = blockIdx.x * 8, h = blockIdx.y, t = threadIdx.x;
    int d = t & 127, half = t >> 7;
    __shared__ float exr[8 * 128], nk[8 * 128], pr[8 * 128];
    for (int idx = t; idx < 8 * 128; idx += 256) {
        exr[idx] = ex_embed[(size_t)i0 * 128 + idx];
        nk[idx]  = new_kc[((size_t)h * N_EX + i0) * 128 + idx];
    }
    __syncthreads();
    const float* Eh = E + h * 16384;
    float acc2[4] = {0.f, 0.f, 0.f, 0.f};
    for (int k = 0; k < 128; ++k) {
        float ev = Eh[k * 128 + d];
#pragma unroll
        for (int r = 0; r < 4; ++r) acc2[r] += exr[(half * 4 + r) * 128 + k] * ev;
    }
#pragma unroll
    for (int r = 0; r < 4; ++r) {
        int rr = half * 4 + r;
        pr[rr * 128 + d] = nk[rr * 128 + d] * acc2[r];
    }
    __syncthreads();
    const float* rt = rd_wT + h * 256 * 128;
    float acc3[4] = {0.f, 0.f, 0.f, 0.f};
    for (int c = 0; c < 128; ++c) {
        float w = rt[c * 128 + d];
#pragma unroll
        for (int r = 0; r < 4; ++r) acc3[r] += nk[(half * 4 + r) * 128 + c] * w;
    }
    for (int c = 0; c < 128; ++c) {
        float w = rt[(128 + c) * 128 + d];
#pragma unroll
        for (int r = 0; r < 4; ++r) acc3[r] += pr[(half * 4 + r) * 128 + c] * w;
    }
#pragma unroll
    for (int r = 0; r < 4; ++r) {
        int rr = half * 4 + r;
        float v = acc3[r] + rd_b[h * 128 + d];
        v = (v > 0.f) ? v : expm1f(v);
        H[((size_t)h * N_EX + i0 + rr) * 128 + d] = v;
    }
}

// ---------------- merge heads ----------------
__global__ void k_merge(const float* H, float* emb_e) {
    int idx = blockIdx.x * blockDim.x + threadIdx.x;
    if (idx >= N_EX * 128) return;
    int i = idx >> 7, d = idx & 127;
    int hs = d >> 6;
    int c0 = (2 * d) & 127, c1 = (2 * d + 1) & 127;
    const float* row = H + ((size_t)hs * N_EX + i) * 128;
    emb_e[idx] = 0.5f * (row[c0] + row[c1]);
}

// ---------------- projC/assessP (16 exercises / block) ----------------
__global__ __launch_bounds__(512) void k_proj(const float* emb_e, const float* w_ihT0,
                                              const float* w_ihT1, const float* fc1_BT,
                                              const float* gbias4,
                                              float* projC, float* assessP) {
    int i0 = blockIdx.x * 16, g = threadIdx.x;
    int gate = g >> 7, uu = g & 127;
    int oidx = uu * 4 + gate;
    float gbl = gbias4[oidx];
    __shared__ float er[16 * 128];
    for (int idx = g; idx < 16 * 128; idx += 512) er[idx] = emb_e[(size_t)i0 * 128 + idx];
    __syncthreads();
    float a0[16], a1[16];
#pragma unroll
    for (int r = 0; r < 16; ++r) { a0[r] = 0.f; a1[r] = 0.f; }
    for (int k = 0; k < 128; ++k) {
        float w0 = w_ihT0[k * 512 + g], w1 = w_ihT1[k * 512 + g];
#pragma unroll
        for (int r = 0; r < 16; ++r) { float e = er[r * 128 + k]; a0[r] += e * w0; a1[r] += e * w1; }
    }
    for (int r = 0; r < 16; ++r) {
        projC[((size_t)(1 + i0 + r)) * 512 + oidx]        = a1[r] + gbl;   // respond 1..N_EX
        projC[((size_t)(1 + N_EX + i0 + r)) * 512 + oidx] = a0[r] + gbl;   // respond N_EX+1..2N_EX
    }
    if (g < 128) {
        float b[16];
#pragma unroll
        for (int r = 0; r < 16; ++r) b[r] = 0.f;
        for (int k = 0; k < 128; ++k) {
            float w = fc1_BT[k * 128 + g];
#pragma unroll
            for (int r = 0; r < 16; ++r) b[r] += er[r * 128 + k] * w;
        }
        for (int r = 0; r < 16; ++r) assessP[((size_t)i0 + r) * 128 + g] = b[r];
    }
}

// ---------------- persistent LSTM: one block per batch element ----------------
// R8 structure (f16 weights + v_dot2_f32_f16, 421 us) + dual-pipe weight sourcing:
// frags 0-6 (57 KB) staged ONCE into static LDS (separate LDS pipe, ~670 cyc/step),
// frags 7-15 (72 KB/step) streamed from L2 (drops aggregate L2 traffic 39 -> ~28 TB/s,
// under the measured 36.9 ceiling; per-CU port load -44%). The two streams overlap.
__global__ __launch_bounds__(512, 2) void k_lstm(const uint4* __restrict__ w16,
                                                 const float* __restrict__ projC,
                                                 const int* __restrict__ respond,
                                                 float* __restrict__ learn) {
    int b = blockIdx.x, t = threadIdx.x;
    int u = t >> 2, q = t & 3;
    __shared__ uint4 wlds[7 * 512];         // 57344 B: weight frags 0..6
    __shared__ uint4 hbuf4[2][18];          // 128 f16 h + pad, per parity
    __shared__ int rrow[500];
    for (int i = t; i < 7 * 512; i += 512) wlds[i] = w16[i];
    for (int s = t; s < 500; s += 512) rrow[s] = respond[b * 500 + s];
    if (t < 36) { uint4 z = {0u, 0u, 0u, 0u}; ((uint4*)hbuf4)[t] = z; }
    float c = 0.f;
    __syncthreads();
    vf4 xg_n = ((const vf4*)(projC + (size_t)rrow[0] * 512))[u];
    const uint4* gbase = w16 + 7 * 512 + t;
    for (int s = 0; s < 500; ++s) {
        int par = s & 1;
        vf4 xg = xg_n;
        if (s < 499) xg_n = ((const vf4*)(projC + (size_t)rrow[s + 1] * 512))[u];
        // h segment for this quad-lane: 32 f16 = 4 uint4
        const uint4* hsegp = (const uint4*)((const unsigned short*)hbuf4[par] + q * 32);
        uint4 h4[4];
#pragma unroll
        for (int j = 0; j < 4; ++j) h4[j] = hsegp[j];
        uint4 wg[9];
#pragma unroll
        for (int i = 0; i < 9; ++i) wg[i] = gbase[i * 512];
        uint4 wl[7];
#pragma unroll
        for (int i = 0; i < 7; ++i) wl[i] = wlds[i * 512 + t];
        uint4 W0[4] = {wl[0], wl[1], wl[2], wl[3]};     // gate i
        uint4 W1[4] = {wl[4], wl[5], wl[6], wg[0]};     // gate f
        uint4 W2[4] = {wg[1], wg[2], wg[3], wg[4]};     // gate g
        uint4 W3[4] = {wg[5], wg[6], wg[7], wg[8]};     // gate o
        float p0 = 0.f, p1 = 0.f, p2 = 0.f, p3 = 0.f;
#pragma unroll
        for (int j = 0; j < 4; ++j) {
            hf2 ha = u2h(h4[j].x), hb = u2h(h4[j].y), hc = u2h(h4[j].z), hd = u2h(h4[j].w);
            p0 = __builtin_amdgcn_fdot2(u2h(W0[j].x), ha, p0, false);
            p0 = __builtin_amdgcn_fdot2(u2h(W0[j].y), hb, p0, false);
            p0 = __builtin_amdgcn_fdot2(u2h(W0[j].z), hc, p0, false);
            p0 = __builtin_amdgcn_fdot2(u2h(W0[j].w), hd, p0, false);
            p1 = __builtin_amdgcn_fdot2(u2h(W1[j].x), ha, p1, false);
            p1 = __builtin_amdgcn_fdot2(u2h(W1[j].y), hb, p1, false);
            p1 = __builtin_amdgcn_fdot2(u2h(W1[j].z), hc, p1, false);
            p1 = __builtin_amdgcn_fdot2(u2h(W1[j].w), hd, p1, false);
            p2 = __builtin_amdgcn_fdot2(u2h(W2[j].x), ha, p2, false);
            p2 = __builtin_amdgcn_fdot2(u2h(W2[j].y), hb, p2, false);
            p2 = __builtin_amdgcn_fdot2(u2h(W2[j].z), hc, p2, false);
            p2 = __builtin_amdgcn_fdot2(u2h(W2[j].w), hd, p2, false);
            p3 = __builtin_amdgcn_fdot2(u2h(W3[j].x), ha, p3, false);
            p3 = __builtin_amdgcn_fdot2(u2h(W3[j].y), hb, p3, false);
            p3 = __builtin_amdgcn_fdot2(u2h(W3[j].z), hc, p3, false);
            p3 = __builtin_amdgcn_fdot2(u2h(W3[j].w), hd, p3, false);
        }
        float gi = quad_sum(p0) + xg.x;
        float gf = quad_sum(p1) + xg.y;
        float gG = quad_sum(p2) + xg.z;
        float go = quad_sum(p3) + xg.w;
        float ii = sigm(gi), ff = sigm(gf), tg = tanh_fast(gG), oo = sigm(go);
        c = ff * c + ii * tg;
        float hh = oo * tanh_fast(c);
        if (q == 0) {
            union { unsigned short us; _Float16 hf; } cv; cv.hf = (_Float16)hh;
            ((unsigned short*)hbuf4[par ^ 1])[u] = cv.us;
            if (s < 499) learn[((size_t)b * 499 + s) * 128 + u] = hh;
        }
        __syncthreads();
    }
}

// ---------------- fused MLP head + sigmoid + BCE loss + t copy ----------------
__global__ __launch_bounds__(256) void k_mlp(const float* __restrict__ learn,
                                             const float* __restrict__ assessP,
                                             const float* __restrict__ fc1_AT,
                                             const float* __restrict__ fc1_b,
                                             const float* __restrict__ fc2_w,
                                             const float* __restrict__ fc2_b,
                                             const int* __restrict__ exercise_data,
                                             const float* __restrict__ target,
                                             float* __restrict__ out,
                                             float* __restrict__ loss_accum) {
    int tile = blockIdx.x;
    int t = threadIdx.x;
    int jg = t & 31, rg = t >> 5;
    __shared__ float A_lds[64 * 128];
    __shared__ float x_lds[64 * 64];
    __shared__ float red[8];
    float4 acc[8];
#pragma unroll
    for (int r = 0; r < 8; ++r) acc[r] = make_float4(0.f, 0.f, 0.f, 0.f);
    int row0 = tile * 64;
    for (int kc = 0; kc < 2; ++kc) {
        for (int idx = t; idx < 64 * 128; idx += 256) A_lds[idx] = fc1_AT[kc * 64 * 128 + idx];
        for (int idx = t; idx < 64 * 64; idx += 256) {
            int r = idx >> 6, k = idx & 63;
            x_lds[idx] = learn[((size_t)row0 + r) * 128 + kc * 64 + k];
        }
        __syncthreads();
        const float4* A4 = (const float4*)A_lds;
        const float4* x4 = (const float4*)x_lds;
#pragma unroll 4
        for (int k4 = 0; k4 < 16; ++k4) {
            float4 av[4];
#pragma unroll
            for (int kk = 0; kk < 4; ++kk) av[kk] = A4[(k4 * 4 + kk) * 32 + jg];
#pragma unroll
            for (int r = 0; r < 8; ++r) {
                float4 xv = x4[(rg * 8 + r) * 16 + k4];
                acc[r].x += xv.x * av[0].x + xv.y * av[1].x + xv.z * av[2].x + xv.w * av[3].x;
                acc[r].y += xv.x * av[0].y + xv.y * av[1].y + xv.z * av[2].y + xv.w * av[3].y;
                acc[r].z += xv.x * av[0].z + xv.y * av[1].z + xv.z * av[2].z + xv.w * av[3].z;
                acc[r].w += xv.x * av[0].w + xv.y * av[1].w + xv.z * av[2].w + xv.w * av[3].w;
            }
        }
        __syncthreads();
    }
    int j = jg * 4;
    float4 b1 = *(const float4*)(fc1_b + j);
    float4 f2 = *(const float4*)(fc2_w + j);
    float fb2 = fc2_b[0];
    float lloss = 0.f;
#pragma unroll
    for (int r = 0; r < 8; ++r) {
        int n = row0 + rg * 8 + r;
        int b = n / 499;
        int sidx = n - b * 499;
        int e = exercise_data[b * 500 + sidx + 1];
        float4 aP = make_float4(0.f, 0.f, 0.f, 0.f);
        if (e > 0) aP = *(const float4*)(assessP + (size_t)(e - 1) * 128 + j);
        float y0 = acc[r].x + aP.x + b1.x; y0 = y0 > 0.f ? y0 : 0.f;
        float y1 = acc[r].y + aP.y + b1.y; y1 = y1 > 0.f ? y1 : 0.f;
        float y2 = acc[r].z + aP.z + b1.z; y2 = y2 > 0.f ? y2 : 0.f;
        float y3 = acc[r].w + aP.w + b1.w; y3 = y3 > 0.f ? y3 : 0.f;
        float s = y0 * f2.x + y1 * f2.y + y2 * f2.z + y3 * f2.w;
#pragma unroll
        for (int m = 16; m > 0; m >>= 1) s += __shfl_xor(s, m, 32);
        if (jg == 0) {
            float p = s + fb2;
            float tg = target[n];
            out[1 + n] = 1.f / (1.f + expf(-p));
            float ab = fabsf(p);
            lloss += fmaxf(p, 0.f) - p * tg + log1pf(expf(-ab));
            out[1 + NROWS + n] = tg;
        }
    }
    if (jg == 0) red[rg] = lloss;
    __syncthreads();
    if (t == 0) {
        float sum = 0.f;
#pragma unroll
        for (int g = 0; g < 8; ++g) sum += red[g];
        atomicAdd(loss_accum, sum);
    }
}

__global__ void k_final(const float* loss_accum, float* out) {
    out[0] = loss_accum[0] * (1.f / (float)NROWS);
}

extern "C" void kernel_launch(void* const* d_in, const int* in_sizes, int n_in,
                              void* d_out, int out_size, void* d_ws, size_t ws_size,
                              hipStream_t stream) {
    const int* adj            = (const int*)d_in[0];
    const int* exercise_data  = (const int*)d_in[2];
    const int* respond        = (const int*)d_in[3];
    const float* target       = (const float*)d_in[4];
    const float* ex_embed     = (const float*)d_in[5];
    const float* kc_embed     = (const float*)d_in[6];
    const float* W1           = (const float*)d_in[7];
    const float* a_att        = (const float*)d_in[8];
    const float* E            = (const float*)d_in[9];
    const float* rd_w         = (const float*)d_in[10];
    const float* rd_b         = (const float*)d_in[11];
    const float* w_ih         = (const float*)d_in[12];
    const float* w_hh         = (const float*)d_in[13];
    const float* b_ih         = (const float*)d_in[14];
    const float* b_hh         = (const float*)d_in[15];
    const float* fc1_w        = (const float*)d_in[16];
    const float* fc1_b        = (const float*)d_in[17];
    const float* fc2_w        = (const float*)d_in[18];
    const float* fc2_b        = (const float*)d_in[19];
    float* out = (float*)d_out;

    float* ws = (float*)d_ws;
    size_t off = 0;
    auto alloc = [&](size_t n) { float* p = ws + off; off += (n + 3) & ~(size_t)3; return p; };
    float* kc_Wh   = alloc(2 * 500 * 128);
    float* s_kc    = alloc(1000);
    float* v1      = alloc(256);
    float* s_ex    = alloc(2 * N_EX);
    float* H       = alloc((size_t)2 * N_EX * 128);
    float* emb_e   = alloc((size_t)N_EX * 128);
    float* rd_wT   = alloc(2 * 256 * 128);
    float* w_ihT0  = alloc(128 * 512);
    float* w_ihT1  = alloc(128 * 512);
    float* fc1_AT  = alloc(128 * 128);
    float* fc1_BT  = alloc(128 * 128);
    float* gbias4  = alloc(512);
    float* wlstm   = alloc(32768);     // 65536 f16
    float* new_kc  = alloc((size_t)2 * N_EX * 128);
    float* projC   = alloc((size_t)(2 * N_EX + 1) * 512);
    float* assessP = alloc((size_t)N_EX * 128);
    float* learn   = alloc((size_t)BB * 499 * 128);
    float* loss_accum = alloc(4);

    k_precomp<<<256, 256, 0, stream>>>(rd_w, w_ih, fc1_w, b_ih, b_hh, W1, a_att, w_hh,
                                       rd_wT, w_ihT0, w_ihT1, fc1_AT, fc1_BT, gbias4, v1,
                                       (unsigned short*)wlstm, projC);
    k_kc<<<dim3(500, 2), 128, 0, stream>>>(kc_embed, W1, a_att, kc_Wh, s_kc);
    k_sex<<<79, 256, 0, stream>>>(ex_embed, v1, s_ex);
    k_attnk<<<dim3(N_EX / 8, 2), 256, 0, stream>>>(adj, s_ex, s_kc, kc_Wh, new_kc);
    k_gat2<<<dim3(N_EX / 8, 2), 256, 0, stream>>>(new_kc, ex_embed, E, rd_wT, rd_b, H);
    k_merge<<<(N_EX * 128) / 256, 256, 0, stream>>>(H, emb_e);
    k_proj<<<N_EX / 16, 512, 0, stream>>>(emb_e, w_ihT0, w_ihT1, fc1_BT, gbias4, projC, assessP);
    hipMemsetAsync(loss_accum, 0, sizeof(float), stream);
    k_lstm<<<BB, 512, 0, stream>>>((const uint4*)wlstm, projC, respond, learn);
    k_mlp<<<NROWS / 64, 256, 0, stream>>>(learn, assessP, fc1_AT, fc1_b, fc2_w, fc2_b,
                                          exercise_data, target, out, loss_accum);
    k_final<<<1, 1, 0, stream>>>(loss_accum, out);
}

// Round 10
// 803.154 us; speedup vs baseline: 1.0204x; 1.0204x over previous
//
#include <hip/hip_runtime.h>
#include <math.h>

#define N_EX 10000
#define N_KC 500
#define D 128
#define HID 128
#define BB 256
#define SS 500
#define NROWS 127744   // B*(S-1)

typedef float vf4 __attribute__((ext_vector_type(4)));
typedef _Float16 hf2 __attribute__((ext_vector_type(2)));

__device__ __forceinline__ float sigm(float x) { return 1.f / (1.f + __expf(-x)); }
__device__ __forceinline__ float tanh_fast(float x) { return 1.f - 2.f / (1.f + __expf(2.f * x)); }

__device__ __forceinline__ hf2 u2h(unsigned v) { union { unsigned u; hf2 h; } x; x.u = v; return x.h; }

// quad-lane sum via DPP quad_perm (VALU pipe, no LDS)
__device__ __forceinline__ float quad_sum(float x) {
    int a = __builtin_amdgcn_update_dpp(0, __float_as_int(x), 0xB1, 0xF, 0xF, true); // xor 1
    x += __int_as_float(a);
    int b = __builtin_amdgcn_update_dpp(0, __float_as_int(x), 0x4E, 0xF, 0xF, true); // xor 2
    x += __int_as_float(b);
    return x;
}

// ---------------- precompute ----------------
__global__ void k_precomp(const float* rd_w, const float* w_ih, const float* fc1_w,
                          const float* b_ih, const float* b_hh, const float* W1, const float* a_att,
                          const float* w_hh,
                          float* rd_wT, float* w_ihT0, float* w_ihT1,
                          float* fc1_AT, float* fc1_BT, float* gbias4, float* v1,
                          unsigned short* wlstm16, float* projC) {
    int idx = blockIdx.x * blockDim.x + threadIdx.x;
    int stride = gridDim.x * blockDim.x;
    const int N1 = 2 * 256 * 128;
    const int N2 = 128 * 512;
    const int N3 = 128 * 512;
    const int N4 = 128 * 128;
    const int N5 = 128 * 128;
    const int N6 = 512;
    const int N7 = 256;
    const int N8 = 65536;
    int total = N1 + N2 + N3 + N4 + N5 + N6 + N7 + N8;
    for (int tt = idx; tt < total; tt += stride) {
        int u = tt;
        if (u < N1) {
            int h = u / (256 * 128); int rem = u % (256 * 128); int c = rem / 128; int dd = rem % 128;
            rd_wT[u] = rd_w[h * 128 * 256 + dd * 256 + c];
        } else if ((u -= N1) < N2) {
            int k = u / 512, g = u % 512; w_ihT0[u] = w_ih[g * 256 + k];
        } else if ((u -= N2) < N3) {
            int k = u / 512, g = u % 512; w_ihT1[u] = w_ih[g * 256 + 128 + k];
        } else if ((u -= N3) < N4) {
            int k = u / 128, j = u % 128; fc1_AT[u] = fc1_w[j * 256 + k];
        } else if ((u -= N4) < N5) {
            int k = u / 128, j = u % 128; fc1_BT[u] = fc1_w[j * 256 + 128 + k];
        } else if ((u -= N5) < N6) {
            int uu = u >> 2, g = u & 3;
            float v = b_ih[g * 128 + uu] + b_hh[g * 128 + uu];
            gbias4[u] = v;
            projC[u] = v;                 // respond==0 row
        } else if ((u -= N6) < N7) {
            int h = u / 128, k = u % 128;
            const float* wr = W1 + h * 16384 + k * 128;
            const float* av = a_att + h * 256;
            float acc = 0.f;
            for (int d = 0; d < 128; ++d) acc += wr[d] * av[d];
            v1[u] = acc;
        } else {
            u -= N7;
            int x = u & 7;
            int t = (u >> 3) & 511;
            int i = u >> 12;
            int g = i >> 2, j = i & 3;
            int uu = t >> 2, q = t & 3;
            float val = w_hh[(g * 128 + uu) * 128 + q * 32 + j * 8 + x];
            ((_Float16*)wlstm16)[u] = (_Float16)val;
        }
    }
}

// ---------------- kc_Wh (transposed) + s_kc ----------------
// kcWhT[(h*128+d)*500 + j] = (kc_embed @ W1h)[j][d]  -- d-major for per-thread b128 streams
__global__ void k_kc(const float* kc_embed, const float* W1, const float* a_att,
                     float* kcWhT, float* s_kc) {
    int j = blockIdx.x, h = blockIdx.y, d = threadIdx.x;
    __shared__ float row[128];
    __shared__ float red[128];
    row[d] = kc_embed[j * 128 + d];
    __syncthreads();
    const float* w = W1 + h * 16384;
    float acc = 0.f;
    for (int k = 0; k < 128; ++k) acc += row[k] * w[k * 128 + d];
    kcWhT[((size_t)(h * 128 + d)) * 500 + j] = acc;
    red[d] = acc * a_att[h * 256 + 128 + d];
    __syncthreads();
    for (int s = 64; s > 0; s >>= 1) { if (d < s) red[d] += red[d + s]; __syncthreads(); }
    if (d == 0) s_kc[h * 500 + j] = red[0];
}

// ---------------- s_ex[h][i] = ex_embed[i] . v1[h] ----------------
__global__ void k_sex(const float* ex_embed, const float* v1, float* s_ex) {
    int t = blockIdx.x * blockDim.x + threadIdx.x;
    if (t >= 2 * N_EX) return;
    int h = t / N_EX, i = t % N_EX;
    const float4* e4 = (const float4*)(ex_embed + (size_t)i * 128);
    const float4* v4 = (const float4*)(v1 + h * 128);
    float acc = 0.f;
    for (int k = 0; k < 32; ++k) {
        float4 a = e4[k], b = v4[k];
        acc += a.x * b.x + a.y * b.y + a.z * b.z + a.w * b.w;
    }
    s_ex[h * N_EX + i] = acc;
}

// ---------------- fused attention softmax + new_kc GEMV (8 rows / block) ----------------
// att stored at[j*12 + r] (stride-12 floats, 16B-aligned groups): the GEMV reads ONE
// broadcast ds_read_b128 per j (vs 4 ds_read_b32 before) and streams kcWhT rows as
// per-thread contiguous b128 -- cuts the LDS-pipe time ~7x.
__global__ __launch_bounds__(256) void k_attnk(const int* adj, const float* s_ex, const float* s_kc,
                                               const float* kcWhT, float* new_kc) {
    int i0 = blockIdx.x * 8, h = blockIdx.y, t = threadIdx.x;
    __shared__ vf4 at4[1500];               // 500*12 floats
    __shared__ float skc_l[500];
    float* at = (float*)at4;
    for (int j = t; j < 500; j += 256) skc_l[j] = s_kc[h * 500 + j];
    __syncthreads();
    {
        int lg = t >> 5, lane = t & 31;
        int i = i0 + lg;
        float sex = s_ex[h * N_EX + i];
        const int* arow = adj + (size_t)i * 500;
        float lmax = -INFINITY;
        for (int j = lane; j < 500; j += 32) {
            float e = sex + skc_l[j];
            e = (e >= 0.f) ? e : 0.2f * e;
            e = (arow[j] > 0) ? e : -INFINITY;
            at[j * 12 + lg] = e;
            lmax = fmaxf(lmax, e);
        }
#pragma unroll
        for (int m = 16; m > 0; m >>= 1) lmax = fmaxf(lmax, __shfl_xor(lmax, m));
        float lsum = 0.f;
        for (int j = lane; j < 500; j += 32) {
            float w = __expf(at[j * 12 + lg] - lmax);
            at[j * 12 + lg] = w;
            lsum += w;
        }
#pragma unroll
        for (int m = 16; m > 0; m >>= 1) lsum += __shfl_xor(lsum, m);
        float inv = 1.f / lsum;
        for (int j = lane; j < 500; j += 32) at[j * 12 + lg] *= inv;
    }
    __syncthreads();
    int d = t & 127, half = t >> 7;
    const float* kcwd = kcWhT + ((size_t)(h * 128 + d)) * 500;
    vf4 acc = {0.f, 0.f, 0.f, 0.f};
    for (int j4 = 0; j4 < 125; ++j4) {
        vf4 w = *(const vf4*)(kcwd + j4 * 4);
        vf4 a0 = *(const vf4*)(at + (j4 * 4 + 0) * 12 + half * 4);
        vf4 a1 = *(const vf4*)(at + (j4 * 4 + 1) * 12 + half * 4);
        vf4 a2 = *(const vf4*)(at + (j4 * 4 + 2) * 12 + half * 4);
        vf4 a3 = *(const vf4*)(at + (j4 * 4 + 3) * 12 + half * 4);
        acc += a0 * w.x + a1 * w.y + a2 * w.z + a3 * w.w;
    }
    new_kc[((size_t)h * N_EX + i0 + half * 4 + 0) * 128 + d] = acc.x;
    new_kc[((size_t)h * N_EX + i0 + half * 4 + 1) * 128 + d] = acc.y;
    new_kc[((size_t)h * N_EX + i0 + half * 4 + 2) * 128 + d] = acc.z;
    new_kc[((size_t)h * N_EX + i0 + half * 4 + 3) * 128 + d] = acc.w;
}

// ---------------- GAT tail: ex@E, readout, ELU   (8 rows / block) ----------------
// Transposed LDS tiles exrT/nkT/prT[k][r] (row stride 8): the three 128-iteration dot
// loops read ONE broadcast b128 per k instead of 4 b32.
__global__ __launch_bounds__(256) void k_gat2(const float* new_kc, const float* ex_embed,
                                              const float* E, const float* rd_wT,
                                              const float* rd_b, float* H) {
    int i0 = blockIdx.x * 8, h = blockIdx.y, t = threadIdx.x;
    int d = t & 127, half = t >> 7;
    __shared__ vf4 exrT4[256], nkT4[256], prT4[256];   // [k][8 rows] as 2 vf4 per k
    float* exrT = (float*)exrT4;
    float* nkT  = (float*)nkT4;
    float* prT  = (float*)prT4;
    for (int idx = t; idx < 8 * 128; idx += 256) {
        int r = idx >> 7, k = idx & 127;
        exrT[k * 8 + r] = ex_embed[(size_t)i0 * 128 + idx];
        nkT[k * 8 + r]  = new_kc[((size_t)h * N_EX + i0) * 128 + idx];
    }
    __syncthreads();
    const float* Eh = E + h * 16384;
    vf4 acc2 = {0.f, 0.f, 0.f, 0.f};
    for (int k = 0; k < 128; ++k) {
        float ev = Eh[k * 128 + d];
        vf4 ex4 = *(const vf4*)(exrT + k * 8 + half * 4);
        acc2 += ex4 * ev;
    }
    {
        vf4 nk4 = *(const vf4*)(nkT + d * 8 + half * 4);
        vf4 pr4 = nk4 * acc2;
        *(vf4*)(prT + d * 8 + half * 4) = pr4;
    }
    __syncthreads();
    const float* rt = rd_wT + h * 256 * 128;
    vf4 acc3 = {0.f, 0.f, 0.f, 0.f};
    for (int c = 0; c < 128; ++c) {
        float w = rt[c * 128 + d];
        vf4 nk4 = *(const vf4*)(nkT + c * 8 + half * 4);
        acc3 += nk4 * w;
    }
    for (int c = 0; c < 128; ++c) {
        float w = rt[(128 + c) * 128 + d];
        vf4 pr4 = *(const vf4*)(prT + c * 8 + half * 4);
        acc3 += pr4 * w;
    }
    float rb = rd_b[h * 128 + d];
#pragma unroll
    for (int r = 0; r < 4; ++r) {
        float v = ((r == 0) ? acc3.x : (r == 1) ? acc3.y : (r == 2) ? acc3.z : acc3.w) + rb;
        v = (v > 0.f) ? v : expm1f(v);
        H[((size_t)h * N_EX + i0 + half * 4 + r) * 128 + d] = v;
    }
}

// ---------------- merge heads ----------------
__global__ void k_merge(const float* H, float* emb_e) {
    int idx = blockIdx.x * blockDim.x + threadIdx.x;
    if (idx >= N_EX * 128) return;
    int i = idx >> 7, d = idx & 127;
    int hs = d >> 6;
    int c0 = (2 * d) & 127, c1 = (2 * d + 1) & 127;
    const float* row = H + ((size_t)hs * N_EX + i) * 128;
    emb_e[idx] = 0.5f * (row[c0] + row[c1]);
}

// ---------------- projC/assessP (16 exercises / block) ----------------
__global__ __launch_bounds__(512) void k_proj(const float* emb_e, const float* w_ihT0,
                                              const float* w_ihT1, const float* fc1_BT,
                                              const float* gbias4,
                                              float* projC, float* assessP) {
    int i0 = blockIdx.x * 16, g = threadIdx.x;
    int gate = g >> 7, uu = g & 127;
    int oidx = uu * 4 + gate;
    float gbl = gbias4[oidx];
    __shared__ float er[16 * 128];
    for (int idx = g; idx < 16 * 128; idx += 512) er[idx] = emb_e[(size_t)i0 * 128 + idx];
    __syncthreads();
    float a0[16], a1[16];
#pragma unroll
    for (int r = 0; r < 16; ++r) { a0[r] = 0.f; a1[r] = 0.f; }
    for (int k = 0; k < 128; ++k) {
        float w0 = w_ihT0[k * 512 + g], w1 = w_ihT1[k * 512 + g];
#pragma unroll
        for (int r = 0; r < 16; ++r) { float e = er[r * 128 + k]; a0[r] += e * w0; a1[r] += e * w1; }
    }
    for (int r = 0; r < 16; ++r) {
        projC[((size_t)(1 + i0 + r)) * 512 + oidx]        = a1[r] + gbl;   // respond 1..N_EX
        projC[((size_t)(1 + N_EX + i0 + r)) * 512 + oidx] = a0[r] + gbl;   // respond N_EX+1..2N_EX
    }
    if (g < 128) {
        float b[16];
#pragma unroll
        for (int r = 0; r < 16; ++r) b[r] = 0.f;
        for (int k = 0; k < 128; ++k) {
            float w = fc1_BT[k * 128 + g];
#pragma unroll
            for (int r = 0; r < 16; ++r) b[r] += er[r * 128 + k] * w;
        }
        for (int r = 0; r < 16; ++r) assessP[((size_t)i0 + r) * 128 + g] = b[r];
    }
}

// ---------------- persistent LSTM (R8 structure, learn stored f16) ----------------
__global__ __launch_bounds__(512, 2) void k_lstm(const uint4* __restrict__ w16,
                                                 const float* __restrict__ projC,
                                                 const int* __restrict__ respond,
                                                 unsigned short* __restrict__ learn16) {
    int b = blockIdx.x, t = threadIdx.x;
    int u = t >> 2, q = t & 3;
    __shared__ uint4 hbuf4[2][18];          // 128 f16 h + pad, per parity
    __shared__ int rrow[500];
    uint4 w[16];
#pragma unroll
    for (int i = 0; i < 16; ++i) w[i] = w16[i * 512 + t];
    for (int s = t; s < 500; s += 512) rrow[s] = respond[b * 500 + s];
    if (t < 36) { uint4 z = {0u, 0u, 0u, 0u}; ((uint4*)hbuf4)[t] = z; }
    float c = 0.f;
    __syncthreads();
    vf4 xg_n = ((const vf4*)(projC + (size_t)rrow[0] * 512))[u];
    for (int s = 0; s < 500; ++s) {
        int par = s & 1;
        vf4 xg = xg_n;
        if (s < 499) xg_n = ((const vf4*)(projC + (size_t)rrow[s + 1] * 512))[u];
        const uint4* hsegp = (const uint4*)((const unsigned short*)hbuf4[par] + q * 32);
        uint4 h4[4];
#pragma unroll
        for (int j = 0; j < 4; ++j) h4[j] = hsegp[j];
        float p0 = 0.f, p1 = 0.f, p2 = 0.f, p3 = 0.f;
#pragma unroll
        for (int j = 0; j < 4; ++j) {
            hf2 ha = u2h(h4[j].x), hb = u2h(h4[j].y), hc = u2h(h4[j].z), hd = u2h(h4[j].w);
            uint4 w0 = w[j], w1 = w[4 + j], w2 = w[8 + j], w3 = w[12 + j];
            p0 = __builtin_amdgcn_fdot2(u2h(w0.x), ha, p0, false);
            p0 = __builtin_amdgcn_fdot2(u2h(w0.y), hb, p0, false);
            p0 = __builtin_amdgcn_fdot2(u2h(w0.z), hc, p0, false);
            p0 = __builtin_amdgcn_fdot2(u2h(w0.w), hd, p0, false);
            p1 = __builtin_amdgcn_fdot2(u2h(w1.x), ha, p1, false);
            p1 = __builtin_amdgcn_fdot2(u2h(w1.y), hb, p1, false);
            p1 = __builtin_amdgcn_fdot2(u2h(w1.z), hc, p1, false);
            p1 = __builtin_amdgcn_fdot2(u2h(w1.w), hd, p1, false);
            p2 = __builtin_amdgcn_fdot2(u2h(w2.x), ha, p2, false);
            p2 = __builtin_amdgcn_fdot2(u2h(w2.y), hb, p2, false);
            p2 = __builtin_amdgcn_fdot2(u2h(w2.z), hc, p2, false);
            p2 = __builtin_amdgcn_fdot2(u2h(w2.w), hd, p2, false);
            p3 = __builtin_amdgcn_fdot2(u2h(w3.x), ha, p3, false);
            p3 = __builtin_amdgcn_fdot2(u2h(w3.y), hb, p3, false);
            p3 = __builtin_amdgcn_fdot2(u2h(w3.z), hc, p3, false);
            p3 = __builtin_amdgcn_fdot2(u2h(w3.w), hd, p3, false);
        }
        float gi = quad_sum(p0) + xg.x;
        float gf = quad_sum(p1) + xg.y;
        float gG = quad_sum(p2) + xg.z;
        float go = quad_sum(p3) + xg.w;
        float ii = sigm(gi), ff = sigm(gf), tg = tanh_fast(gG), oo = sigm(go);
        c = ff * c + ii * tg;
        float hh = oo * tanh_fast(c);
        if (q == 0) {
            union { unsigned short us; _Float16 hf; } cv; cv.hf = (_Float16)hh;
            ((unsigned short*)hbuf4[par ^ 1])[u] = cv.us;
            if (s < 499) learn16[((size_t)b * 499 + s) * 128 + u] = cv.us;
        }
        __syncthreads();
    }
}

// ---------------- fused MLP head + sigmoid + BCE loss + t copy ----------------
__global__ __launch_bounds__(256) void k_mlp(const unsigned short* __restrict__ learn16,
                                             const float* __restrict__ assessP,
                                             const float* __restrict__ fc1_AT,
                                             const float* __restrict__ fc1_b,
                                             const float* __restrict__ fc2_w,
                                             const float* __restrict__ fc2_b,
                                             const int* __restrict__ exercise_data,
                                             const float* __restrict__ target,
                                             float* __restrict__ out,
                                             float* __restrict__ loss_accum) {
    int tile = blockIdx.x;
    int t = threadIdx.x;
    int jg = t & 31, rg = t >> 5;
    __shared__ float A_lds[64 * 128];
    __shared__ float x_lds[64 * 64];
    __shared__ float red[8];
    float4 acc[8];
#pragma unroll
    for (int r = 0; r < 8; ++r) acc[r] = make_float4(0.f, 0.f, 0.f, 0.f);
    int row0 = tile * 64;
    for (int kc = 0; kc < 2; ++kc) {
        for (int idx = t; idx < 64 * 128; idx += 256) A_lds[idx] = fc1_AT[kc * 64 * 128 + idx];
        for (int idx = t; idx < 64 * 32; idx += 256) {       // pairs of f16
            int r = idx >> 5, k2 = idx & 31;
            unsigned pv = *(const unsigned*)(learn16 + ((size_t)row0 + r) * 128 + kc * 64 + k2 * 2);
            hf2 hp = u2h(pv);
            x_lds[(r << 6) + k2 * 2]     = (float)hp.x;
            x_lds[(r << 6) + k2 * 2 + 1] = (float)hp.y;
        }
        __syncthreads();
        const float4* A4 = (const float4*)A_lds;
        const float4* x4 = (const float4*)x_lds;
#pragma unroll 4
        for (int k4 = 0; k4 < 16; ++k4) {
            float4 av[4];
#pragma unroll
            for (int kk = 0; kk < 4; ++kk) av[kk] = A4[(k4 * 4 + kk) * 32 + jg];
#pragma unroll
            for (int r = 0; r < 8; ++r) {
                float4 xv = x4[(rg * 8 + r) * 16 + k4];
                acc[r].x += xv.x * av[0].x + xv.y * av[1].x + xv.z * av[2].x + xv.w * av[3].x;
                acc[r].y += xv.x * av[0].y + xv.y * av[1].y + xv.z * av[2].y + xv.w * av[3].y;
                acc[r].z += xv.x * av[0].z + xv.y * av[1].z + xv.z * av[2].z + xv.w * av[3].z;
                acc[r].w += xv.x * av[0].w + xv.y * av[1].w + xv.z * av[2].w + xv.w * av[3].w;
            }
        }
        __syncthreads();
    }
    int j = jg * 4;
    float4 b1 = *(const float4*)(fc1_b + j);
    float4 f2 = *(const float4*)(fc2_w + j);
    float fb2 = fc2_b[0];
    float lloss = 0.f;
#pragma unroll
    for (int r = 0; r < 8; ++r) {
        int n = row0 + rg * 8 + r;
        int b = n / 499;
        int sidx = n - b * 499;
        int e = exercise_data[b * 500 + sidx + 1];
        float4 aP = make_float4(0.f, 0.f, 0.f, 0.f);
        if (e > 0) aP = *(const float4*)(assessP + (size_t)(e - 1) * 128 + j);
        float y0 = acc[r].x + aP.x + b1.x; y0 = y0 > 0.f ? y0 : 0.f;
        float y1 = acc[r].y + aP.y + b1.y; y1 = y1 > 0.f ? y1 : 0.f;
        float y2 = acc[r].z + aP.z + b1.z; y2 = y2 > 0.f ? y2 : 0.f;
        float y3 = acc[r].w + aP.w + b1.w; y3 = y3 > 0.f ? y3 : 0.f;
        float s = y0 * f2.x + y1 * f2.y + y2 * f2.z + y3 * f2.w;
#pragma unroll
        for (int m = 16; m > 0; m >>= 1) s += __shfl_xor(s, m, 32);
        if (jg == 0) {
            float p = s + fb2;
            float tg = target[n];
            out[1 + n] = 1.f / (1.f + expf(-p));
            float ab = fabsf(p);
            lloss += fmaxf(p, 0.f) - p * tg + log1pf(expf(-ab));
            out[1 + NROWS + n] = tg;
        }
    }
    if (jg == 0) red[rg] = lloss;
    __syncthreads();
    if (t == 0) {
        float sum = 0.f;
#pragma unroll
        for (int g = 0; g < 8; ++g) sum += red[g];
        atomicAdd(loss_accum, sum);
    }
}

__global__ void k_final(const float* loss_accum, float* out) {
    out[0] = loss_accum[0] * (1.f / (float)NROWS);
}

extern "C" void kernel_launch(void* const* d_in, const int* in_sizes, int n_in,
                              void* d_out, int out_size, void* d_ws, size_t ws_size,
                              hipStream_t stream) {
    const int* adj            = (const int*)d_in[0];
    const int* exercise_data  = (const int*)d_in[2];
    const int* respond        = (const int*)d_in[3];
    const float* target       = (const float*)d_in[4];
    const float* ex_embed     = (const float*)d_in[5];
    const float* kc_embed     = (const float*)d_in[6];
    const float* W1           = (const float*)d_in[7];
    const float* a_att        = (const float*)d_in[8];
    const float* E            = (const float*)d_in[9];
    const float* rd_w         = (const float*)d_in[10];
    const float* rd_b         = (const float*)d_in[11];
    const float* w_ih         = (const float*)d_in[12];
    const float* w_hh         = (const float*)d_in[13];
    const float* b_ih         = (const float*)d_in[14];
    const float* b_hh         = (const float*)d_in[15];
    const float* fc1_w        = (const float*)d_in[16];
    const float* fc1_b        = (const float*)d_in[17];
    const float* fc2_w        = (const float*)d_in[18];
    const float* fc2_b        = (const float*)d_in[19];
    float* out = (float*)d_out;

    float* ws = (float*)d_ws;
    size_t off = 0;
    auto alloc = [&](size_t n) { float* p = ws + off; off += (n + 3) & ~(size_t)3; return p; };
    float* kcWhT   = alloc(2 * 128 * 500);
    float* s_kc    = alloc(1000);
    float* v1      = alloc(256);
    float* s_ex    = alloc(2 * N_EX);
    float* H       = alloc((size_t)2 * N_EX * 128);
    float* emb_e   = alloc((size_t)N_EX * 128);
    float* rd_wT   = alloc(2 * 256 * 128);
    float* w_ihT0  = alloc(128 * 512);
    float* w_ihT1  = alloc(128 * 512);
    float* fc1_AT  = alloc(128 * 128);
    float* fc1_BT  = alloc(128 * 128);
    float* gbias4  = alloc(512);
    float* wlstm   = alloc(32768);     // 65536 f16
    float* new_kc  = alloc((size_t)2 * N_EX * 128);
    float* projC   = alloc((size_t)(2 * N_EX + 1) * 512);
    float* assessP = alloc((size_t)N_EX * 128);
    float* learn16 = alloc((size_t)BB * 499 * 64);   // f16: BB*499*128 u16 = *64 floats
    float* loss_accum = alloc(4);

    k_precomp<<<256, 256, 0, stream>>>(rd_w, w_ih, fc1_w, b_ih, b_hh, W1, a_att, w_hh,
                                       rd_wT, w_ihT0, w_ihT1, fc1_AT, fc1_BT, gbias4, v1,
                                       (unsigned short*)wlstm, projC);
    k_kc<<<dim3(500, 2), 128, 0, stream>>>(kc_embed, W1, a_att, kcWhT, s_kc);
    k_sex<<<79, 256, 0, stream>>>(ex_embed, v1, s_ex);
    k_attnk<<<dim3(N_EX / 8, 2), 256, 0, stream>>>(adj, s_ex, s_kc, kcWhT, new_kc);
    k_gat2<<<dim3(N_EX / 8, 2), 256, 0, stream>>>(new_kc, ex_embed, E, rd_wT, rd_b, H);
    k_merge<<<(N_EX * 128) / 256, 256, 0, stream>>>(H, emb_e);
    k_proj<<<N_EX / 16, 512, 0, stream>>>(emb_e, w_ihT0, w_ihT1, fc1_BT, gbias4, projC, assessP);
    hipMemsetAsync(loss_accum, 0, sizeof(float), stream);
    k_lstm<<<BB, 512, 0, stream>>>((const uint4*)wlstm, projC, respond,
                                   (unsigned short*)learn16);
    k_mlp<<<NROWS / 64, 256, 0, stream>>>((const unsigned short*)learn16, assessP, fc1_AT,
                                          fc1_b, fc2_w, fc2_b,
                                          exercise_data, target, out, loss_accum);
    k_final<<<1, 1, 0, stream>>>(loss_accum, out);
}

// Round 11
// 800.683 us; speedup vs baseline: 1.0235x; 1.0031x over previous
//
#include <hip/hip_runtime.h>
#include <math.h>

#define N_EX 10000
#define N_KC 500
#define D 128
#define HID 128
#define BB 256
#define SS 500
#define NROWS 127744   // B*(S-1)

typedef float vf4 __attribute__((ext_vector_type(4)));
typedef _Float16 hf2 __attribute__((ext_vector_type(2)));

__device__ __forceinline__ float sigm(float x) { return 1.f / (1.f + __expf(-x)); }
__device__ __forceinline__ float tanh_fast(float x) { return 1.f - 2.f / (1.f + __expf(2.f * x)); }

__device__ __forceinline__ hf2 u2h(unsigned v) { union { unsigned u; hf2 h; } x; x.u = v; return x.h; }

// quad-lane sum via DPP quad_perm (VALU pipe, no LDS)
__device__ __forceinline__ float quad_sum(float x) {
    int a = __builtin_amdgcn_update_dpp(0, __float_as_int(x), 0xB1, 0xF, 0xF, true); // xor 1
    x += __int_as_float(a);
    int b = __builtin_amdgcn_update_dpp(0, __float_as_int(x), 0x4E, 0xF, 0xF, true); // xor 2
    x += __int_as_float(b);
    return x;
}

// ---------------- precompute ----------------
// projC layout is gate-major: projC[row*512 + g], g = gate*128 + u (natural w_ih row order).
// Row 0 = bias-only (respond==0). wlstm16 f16 layout unchanged from R8.
__global__ void k_precomp(const float* rd_w, const float* w_ih, const float* fc1_w,
                          const float* b_ih, const float* b_hh, const float* W1, const float* a_att,
                          const float* w_hh,
                          float* rd_wT, float* w_ihT0, float* w_ihT1,
                          float* fc1_AT, float* fc1_BT, float* v1,
                          unsigned short* wlstm16, float* projC) {
    int idx = blockIdx.x * blockDim.x + threadIdx.x;
    int stride = gridDim.x * blockDim.x;
    const int N1 = 2 * 256 * 128;
    const int N2 = 128 * 512;
    const int N3 = 128 * 512;
    const int N4 = 128 * 128;
    const int N5 = 128 * 128;
    const int N6 = 512;
    const int N7 = 256;
    const int N8 = 65536;
    int total = N1 + N2 + N3 + N4 + N5 + N6 + N7 + N8;
    for (int tt = idx; tt < total; tt += stride) {
        int u = tt;
        if (u < N1) {
            int h = u / (256 * 128); int rem = u % (256 * 128); int c = rem / 128; int dd = rem % 128;
            rd_wT[u] = rd_w[h * 128 * 256 + dd * 256 + c];
        } else if ((u -= N1) < N2) {
            int k = u / 512, g = u % 512; w_ihT0[u] = w_ih[g * 256 + k];
        } else if ((u -= N2) < N3) {
            int k = u / 512, g = u % 512; w_ihT1[u] = w_ih[g * 256 + 128 + k];
        } else if ((u -= N3) < N4) {
            int k = u / 128, j = u % 128; fc1_AT[u] = fc1_w[j * 256 + k];
        } else if ((u -= N4) < N5) {
            int k = u / 128, j = u % 128; fc1_BT[u] = fc1_w[j * 256 + 128 + k];
        } else if ((u -= N5) < N6) {
            projC[u] = b_ih[u] + b_hh[u];      // respond==0 row, gate-major
        } else if ((u -= N6) < N7) {
            int h = u / 128, k = u % 128;
            const float* wr = W1 + h * 16384 + k * 128;
            const float* av = a_att + h * 256;
            float acc = 0.f;
            for (int d = 0; d < 128; ++d) acc += wr[d] * av[d];
            v1[u] = acc;
        } else {
            u -= N7;
            int x = u & 7;
            int t = (u >> 3) & 511;
            int i = u >> 12;
            int g = i >> 2, j = i & 3;
            int uu = t >> 2, q = t & 3;
            float val = w_hh[(g * 128 + uu) * 128 + q * 32 + j * 8 + x];
            ((_Float16*)wlstm16)[u] = (_Float16)val;
        }
    }
}

// ---------------- kc_Wh (transposed) + s_kc ----------------
__global__ void k_kc(const float* kc_embed, const float* W1, const float* a_att,
                     float* kcWhT, float* s_kc) {
    int j = blockIdx.x, h = blockIdx.y, d = threadIdx.x;
    __shared__ float row[128];
    __shared__ float red[128];
    row[d] = kc_embed[j * 128 + d];
    __syncthreads();
    const float* w = W1 + h * 16384;
    float acc = 0.f;
    for (int k = 0; k < 128; ++k) acc += row[k] * w[k * 128 + d];
    kcWhT[((size_t)(h * 128 + d)) * 500 + j] = acc;
    red[d] = acc * a_att[h * 256 + 128 + d];
    __syncthreads();
    for (int s = 64; s > 0; s >>= 1) { if (d < s) red[d] += red[d + s]; __syncthreads(); }
    if (d == 0) s_kc[h * 500 + j] = red[0];
}

// ---------------- s_ex[h][i] = ex_embed[i] . v1[h] ----------------
__global__ void k_sex(const float* ex_embed, const float* v1, float* s_ex) {
    int t = blockIdx.x * blockDim.x + threadIdx.x;
    if (t >= 2 * N_EX) return;
    int h = t / N_EX, i = t % N_EX;
    const float4* e4 = (const float4*)(ex_embed + (size_t)i * 128);
    const float4* v4 = (const float4*)(v1 + h * 128);
    float acc = 0.f;
    for (int k = 0; k < 32; ++k) {
        float4 a = e4[k], b = v4[k];
        acc += a.x * b.x + a.y * b.y + a.z * b.z + a.w * b.w;
    }
    s_ex[h * N_EX + i] = acc;
}

// ---------------- fused attention softmax + new_kc GEMV, BOTH heads / block ----------------
// adj row masks read once per block (was twice). at buffers stride-12 (1 broadcast b128/j in GEMV).
__global__ __launch_bounds__(256) void k_attnk(const int* adj, const float* s_ex, const float* s_kc,
                                               const float* kcWhT, float* new_kc) {
    int i0 = blockIdx.x * 8, t = threadIdx.x;
    __shared__ vf4 at4[2][1500];            // 2 heads * 500*12 floats = 48 KB
    __shared__ float skc_l[2][500];
    float* at0 = (float*)at4[0];
    float* at1 = (float*)at4[1];
    for (int j = t; j < 1000; j += 256) ((float*)skc_l)[j] = s_kc[j];
    __syncthreads();
    {
        int lg = t >> 5, lane = t & 31;
        int i = i0 + lg;
        float sex0 = s_ex[i];
        float sex1 = s_ex[N_EX + i];
        const int* arow = adj + (size_t)i * 500;
        float lmax0 = -INFINITY, lmax1 = -INFINITY;
        for (int j = lane; j < 500; j += 32) {
            bool m = arow[j] > 0;
            float e0 = sex0 + skc_l[0][j];
            e0 = (e0 >= 0.f) ? e0 : 0.2f * e0;
            e0 = m ? e0 : -INFINITY;
            float e1 = sex1 + skc_l[1][j];
            e1 = (e1 >= 0.f) ? e1 : 0.2f * e1;
            e1 = m ? e1 : -INFINITY;
            at0[j * 12 + lg] = e0;
            at1[j * 12 + lg] = e1;
            lmax0 = fmaxf(lmax0, e0);
            lmax1 = fmaxf(lmax1, e1);
        }
#pragma unroll
        for (int m = 16; m > 0; m >>= 1) {
            lmax0 = fmaxf(lmax0, __shfl_xor(lmax0, m));
            lmax1 = fmaxf(lmax1, __shfl_xor(lmax1, m));
        }
        float lsum0 = 0.f, lsum1 = 0.f;
        for (int j = lane; j < 500; j += 32) {
            float w0 = __expf(at0[j * 12 + lg] - lmax0);
            float w1 = __expf(at1[j * 12 + lg] - lmax1);
            at0[j * 12 + lg] = w0;
            at1[j * 12 + lg] = w1;
            lsum0 += w0; lsum1 += w1;
        }
#pragma unroll
        for (int m = 16; m > 0; m >>= 1) {
            lsum0 += __shfl_xor(lsum0, m);
            lsum1 += __shfl_xor(lsum1, m);
        }
        float inv0 = 1.f / lsum0, inv1 = 1.f / lsum1;
        for (int j = lane; j < 500; j += 32) {
            at0[j * 12 + lg] *= inv0;
            at1[j * 12 + lg] *= inv1;
        }
    }
    __syncthreads();
    int d = t & 127, half = t >> 7;
    for (int h = 0; h < 2; ++h) {
        const float* at = (h == 0) ? at0 : at1;
        const float* kcwd = kcWhT + ((size_t)(h * 128 + d)) * 500;
        vf4 acc = {0.f, 0.f, 0.f, 0.f};
        for (int j4 = 0; j4 < 125; ++j4) {
            vf4 w = *(const vf4*)(kcwd + j4 * 4);
            vf4 a0 = *(const vf4*)(at + (j4 * 4 + 0) * 12 + half * 4);
            vf4 a1 = *(const vf4*)(at + (j4 * 4 + 1) * 12 + half * 4);
            vf4 a2 = *(const vf4*)(at + (j4 * 4 + 2) * 12 + half * 4);
            vf4 a3 = *(const vf4*)(at + (j4 * 4 + 3) * 12 + half * 4);
            acc += a0 * w.x + a1 * w.y + a2 * w.z + a3 * w.w;
        }
        new_kc[((size_t)h * N_EX + i0 + half * 4 + 0) * 128 + d] = acc.x;
        new_kc[((size_t)h * N_EX + i0 + half * 4 + 1) * 128 + d] = acc.y;
        new_kc[((size_t)h * N_EX + i0 + half * 4 + 2) * 128 + d] = acc.z;
        new_kc[((size_t)h * N_EX + i0 + half * 4 + 3) * 128 + d] = acc.w;
    }
}

// ---------------- fused GAT tail + head merge: ex@E, readout, ELU, mean  (8 rows / block) ----------------
// Both heads computed in-block (H kept in LDS only), merge emits emb_e directly.
// Eliminates the 10 MB H array and the k_merge launch.
__global__ __launch_bounds__(256) void k_gat2m(const float* new_kc, const float* ex_embed,
                                               const float* E, const float* rd_wT,
                                               const float* rd_b, float* emb_e) {
    int i0 = blockIdx.x * 8, t = threadIdx.x;
    int d = t & 127, half = t >> 7;
    __shared__ float exrT[128 * 8];          // [k][r]
    __shared__ float nkT[2][128 * 8];
    __shared__ float prT[128 * 8];
    __shared__ float Hl[2][8 * 128];         // [h][r][d]
    for (int idx = t; idx < 8 * 128; idx += 256) {
        int r = idx >> 7, k = idx & 127;
        exrT[k * 8 + r]   = ex_embed[(size_t)i0 * 128 + idx];
        nkT[0][k * 8 + r] = new_kc[((size_t)i0) * 128 + idx];
        nkT[1][k * 8 + r] = new_kc[((size_t)N_EX + i0) * 128 + idx];
    }
    __syncthreads();
    for (int h = 0; h < 2; ++h) {
        const float* Eh = E + h * 16384;
        const float* rt = rd_wT + h * 256 * 128;
        float rb = rd_b[h * 128 + d];
        vf4 acc2 = {0.f, 0.f, 0.f, 0.f};
        for (int k = 0; k < 128; ++k) {
            float ev = Eh[k * 128 + d];
            vf4 ex4 = *(const vf4*)(exrT + k * 8 + half * 4);
            acc2 += ex4 * ev;
        }
        {
            vf4 nk4 = *(const vf4*)(nkT[h] + d * 8 + half * 4);
            *(vf4*)(prT + d * 8 + half * 4) = nk4 * acc2;
        }
        __syncthreads();
        vf4 acc3 = {0.f, 0.f, 0.f, 0.f};
        for (int c = 0; c < 128; ++c) {
            float w = rt[c * 128 + d];
            vf4 nk4 = *(const vf4*)(nkT[h] + c * 8 + half * 4);
            acc3 += nk4 * w;
        }
        for (int c = 0; c < 128; ++c) {
            float w = rt[(128 + c) * 128 + d];
            vf4 pr4 = *(const vf4*)(prT + c * 8 + half * 4);
            acc3 += pr4 * w;
        }
#pragma unroll
        for (int r = 0; r < 4; ++r) {
            float v = ((r == 0) ? acc3.x : (r == 1) ? acc3.y : (r == 2) ? acc3.z : acc3.w) + rb;
            v = (v > 0.f) ? v : expm1f(v);
            Hl[h][(half * 4 + r) * 128 + d] = v;
        }
        __syncthreads();
    }
    // merge: emb[i][dd] = 0.5*(H[dd>>6][i][2dd&127] + H[dd>>6][i][(2dd+1)&127])
    for (int idx = t; idx < 8 * 128; idx += 256) {
        int r = idx >> 7, dd = idx & 127;
        int hs = dd >> 6;
        int c0 = (2 * dd) & 127, c1 = (2 * dd + 1) & 127;
        emb_e[((size_t)i0 + r) * 128 + dd] = 0.5f * (Hl[hs][r * 128 + c0] + Hl[hs][r * 128 + c1]);
    }
}

// ---------------- projC/assessP (16 exercises / block) ----------------
// projC gate-major: thread g writes offset g -> fully coalesced (was 4x-amplified strided).
__global__ __launch_bounds__(512) void k_proj(const float* emb_e, const float* w_ihT0,
                                              const float* w_ihT1, const float* fc1_BT,
                                              const float* b_ih, const float* b_hh,
                                              float* projC, float* assessP) {
    int i0 = blockIdx.x * 16, g = threadIdx.x;
    float gbl = b_ih[g] + b_hh[g];
    __shared__ float er[16 * 128];
    for (int idx = g; idx < 16 * 128; idx += 512) er[idx] = emb_e[(size_t)i0 * 128 + idx];
    __syncthreads();
    float a0[16], a1[16];
#pragma unroll
    for (int r = 0; r < 16; ++r) { a0[r] = 0.f; a1[r] = 0.f; }
    for (int k = 0; k < 128; ++k) {
        float w0 = w_ihT0[k * 512 + g], w1 = w_ihT1[k * 512 + g];
#pragma unroll
        for (int r = 0; r < 16; ++r) { float e = er[r * 128 + k]; a0[r] += e * w0; a1[r] += e * w1; }
    }
    for (int r = 0; r < 16; ++r) {
        projC[((size_t)(1 + i0 + r)) * 512 + g]        = a1[r] + gbl;   // respond 1..N_EX
        projC[((size_t)(1 + N_EX + i0 + r)) * 512 + g] = a0[r] + gbl;   // respond N_EX+1..2N_EX
    }
    if (g < 128) {
        float b[16];
#pragma unroll
        for (int r = 0; r < 16; ++r) b[r] = 0.f;
        for (int k = 0; k < 128; ++k) {
            float w = fc1_BT[k * 128 + g];
#pragma unroll
            for (int r = 0; r < 16; ++r) b[r] += er[r * 128 + k] * w;
        }
        for (int r = 0; r < 16; ++r) assessP[((size_t)i0 + r) * 128 + g] = b[r];
    }
}

// ---------------- persistent LSTM (R8 engine; gate-major xg gather; learn f16) ----------------
__global__ __launch_bounds__(512, 2) void k_lstm(const uint4* __restrict__ w16,
                                                 const float* __restrict__ projC,
                                                 const int* __restrict__ respond,
                                                 unsigned short* __restrict__ learn16) {
    int b = blockIdx.x, t = threadIdx.x;
    int u = t >> 2, q = t & 3;
    __shared__ uint4 hbuf4[2][18];          // 128 f16 h + pad, per parity
    __shared__ int rrow[500];
    uint4 w[16];
#pragma unroll
    for (int i = 0; i < 16; ++i) w[i] = w16[i * 512 + t];
    for (int s = t; s < 500; s += 512) rrow[s] = respond[b * 500 + s];
    if (t < 36) { uint4 z = {0u, 0u, 0u, 0u}; ((uint4*)hbuf4)[t] = z; }
    float c = 0.f;
    __syncthreads();
    const float* pc0 = projC + (size_t)rrow[0] * 512;
    float x0n = pc0[u], x1n = pc0[128 + u], x2n = pc0[256 + u], x3n = pc0[384 + u];
    for (int s = 0; s < 500; ++s) {
        int par = s & 1;
        float x0 = x0n, x1 = x1n, x2 = x2n, x3 = x3n;
        if (s < 499) {
            const float* pc = projC + (size_t)rrow[s + 1] * 512;
            x0n = pc[u]; x1n = pc[128 + u]; x2n = pc[256 + u]; x3n = pc[384 + u];
        }
        const uint4* hsegp = (const uint4*)((const unsigned short*)hbuf4[par] + q * 32);
        uint4 h4[4];
#pragma unroll
        for (int j = 0; j < 4; ++j) h4[j] = hsegp[j];
        float p0 = 0.f, p1 = 0.f, p2 = 0.f, p3 = 0.f;
#pragma unroll
        for (int j = 0; j < 4; ++j) {
            hf2 ha = u2h(h4[j].x), hb = u2h(h4[j].y), hc = u2h(h4[j].z), hd = u2h(h4[j].w);
            uint4 w0 = w[j], w1 = w[4 + j], w2 = w[8 + j], w3 = w[12 + j];
            p0 = __builtin_amdgcn_fdot2(u2h(w0.x), ha, p0, false);
            p0 = __builtin_amdgcn_fdot2(u2h(w0.y), hb, p0, false);
            p0 = __builtin_amdgcn_fdot2(u2h(w0.z), hc, p0, false);
            p0 = __builtin_amdgcn_fdot2(u2h(w0.w), hd, p0, false);
            p1 = __builtin_amdgcn_fdot2(u2h(w1.x), ha, p1, false);
            p1 = __builtin_amdgcn_fdot2(u2h(w1.y), hb, p1, false);
            p1 = __builtin_amdgcn_fdot2(u2h(w1.z), hc, p1, false);
            p1 = __builtin_amdgcn_fdot2(u2h(w1.w), hd, p1, false);
            p2 = __builtin_amdgcn_fdot2(u2h(w2.x), ha, p2, false);
            p2 = __builtin_amdgcn_fdot2(u2h(w2.y), hb, p2, false);
            p2 = __builtin_amdgcn_fdot2(u2h(w2.z), hc, p2, false);
            p2 = __builtin_amdgcn_fdot2(u2h(w2.w), hd, p2, false);
            p3 = __builtin_amdgcn_fdot2(u2h(w3.x), ha, p3, false);
            p3 = __builtin_amdgcn_fdot2(u2h(w3.y), hb, p3, false);
            p3 = __builtin_amdgcn_fdot2(u2h(w3.z), hc, p3, false);
            p3 = __builtin_amdgcn_fdot2(u2h(w3.w), hd, p3, false);
        }
        float gi = quad_sum(p0) + x0;
        float gf = quad_sum(p1) + x1;
        float gG = quad_sum(p2) + x2;
        float go = quad_sum(p3) + x3;
        float ii = sigm(gi), ff = sigm(gf), tg = tanh_fast(gG), oo = sigm(go);
        c = ff * c + ii * tg;
        float hh = oo * tanh_fast(c);
        if (q == 0) {
            union { unsigned short us; _Float16 hf; } cv; cv.hf = (_Float16)hh;
            ((unsigned short*)hbuf4[par ^ 1])[u] = cv.us;
            if (s < 499) learn16[((size_t)b * 499 + s) * 128 + u] = cv.us;
        }
        __syncthreads();
    }
}

// ---------------- fused MLP head + sigmoid + BCE loss + t copy ----------------
__global__ __launch_bounds__(256) void k_mlp(const unsigned short* __restrict__ learn16,
                                             const float* __restrict__ assessP,
                                             const float* __restrict__ fc1_AT,
                                             const float* __restrict__ fc1_b,
                                             const float* __restrict__ fc2_w,
                                             const float* __restrict__ fc2_b,
                                             const int* __restrict__ exercise_data,
                                             const float* __restrict__ target,
                                             float* __restrict__ out,
                                             float* __restrict__ loss_accum) {
    int tile = blockIdx.x;
    int t = threadIdx.x;
    int jg = t & 31, rg = t >> 5;
    __shared__ float A_lds[64 * 128];
    __shared__ float x_lds[64 * 64];
    __shared__ float red[8];
    float4 acc[8];
#pragma unroll
    for (int r = 0; r < 8; ++r) acc[r] = make_float4(0.f, 0.f, 0.f, 0.f);
    int row0 = tile * 64;
    for (int kc = 0; kc < 2; ++kc) {
        for (int idx = t; idx < 64 * 128; idx += 256) A_lds[idx] = fc1_AT[kc * 64 * 128 + idx];
        for (int idx = t; idx < 64 * 32; idx += 256) {
            int r = idx >> 5, k2 = idx & 31;
            unsigned pv = *(const unsigned*)(learn16 + ((size_t)row0 + r) * 128 + kc * 64 + k2 * 2);
            hf2 hp = u2h(pv);
            x_lds[(r << 6) + k2 * 2]     = (float)hp.x;
            x_lds[(r << 6) + k2 * 2 + 1] = (float)hp.y;
        }
        __syncthreads();
        const float4* A4 = (const float4*)A_lds;
        const float4* x4 = (const float4*)x_lds;
#pragma unroll 4
        for (int k4 = 0; k4 < 16; ++k4) {
            float4 av[4];
#pragma unroll
            for (int kk = 0; kk < 4; ++kk) av[kk] = A4[(k4 * 4 + kk) * 32 + jg];
#pragma unroll
            for (int r = 0; r < 8; ++r) {
                float4 xv = x4[(rg * 8 + r) * 16 + k4];
                acc[r].x += xv.x * av[0].x + xv.y * av[1].x + xv.z * av[2].x + xv.w * av[3].x;
                acc[r].y += xv.x * av[0].y + xv.y * av[1].y + xv.z * av[2].y + xv.w * av[3].y;
                acc[r].z += xv.x * av[0].z + xv.y * av[1].z + xv.z * av[2].z + xv.w * av[3].z;
                acc[r].w += xv.x * av[0].w + xv.y * av[1].w + xv.z * av[2].w + xv.w * av[3].w;
            }
        }
        __syncthreads();
    }
    int j = jg * 4;
    float4 b1 = *(const float4*)(fc1_b + j);
    float4 f2 = *(const float4*)(fc2_w + j);
    float fb2 = fc2_b[0];
    float lloss = 0.f;
#pragma unroll
    for (int r = 0; r < 8; ++r) {
        int n = row0 + rg * 8 + r;
        int b = n / 499;
        int sidx = n - b * 499;
        int e = exercise_data[b * 500 + sidx + 1];
        float4 aP = make_float4(0.f, 0.f, 0.f, 0.f);
        if (e > 0) aP = *(const float4*)(assessP + (size_t)(e - 1) * 128 + j);
        float y0 = acc[r].x + aP.x + b1.x; y0 = y0 > 0.f ? y0 : 0.f;
        float y1 = acc[r].y + aP.y + b1.y; y1 = y1 > 0.f ? y1 : 0.f;
        float y2 = acc[r].z + aP.z + b1.z; y2 = y2 > 0.f ? y2 : 0.f;
        float y3 = acc[r].w + aP.w + b1.w; y3 = y3 > 0.f ? y3 : 0.f;
        float s = y0 * f2.x + y1 * f2.y + y2 * f2.z + y3 * f2.w;
#pragma unroll
        for (int m = 16; m > 0; m >>= 1) s += __shfl_xor(s, m, 32);
        if (jg == 0) {
            float p = s + fb2;
            float tg = target[n];
            out[1 + n] = 1.f / (1.f + expf(-p));
            float ab = fabsf(p);
            lloss += fmaxf(p, 0.f) - p * tg + log1pf(expf(-ab));
            out[1 + NROWS + n] = tg;
        }
    }
    if (jg == 0) red[rg] = lloss;
    __syncthreads();
    if (t == 0) {
        float sum = 0.f;
#pragma unroll
        for (int g = 0; g < 8; ++g) sum += red[g];
        atomicAdd(loss_accum, sum);
    }
}

__global__ void k_final(const float* loss_accum, float* out) {
    out[0] = loss_accum[0] * (1.f / (float)NROWS);
}

extern "C" void kernel_launch(void* const* d_in, const int* in_sizes, int n_in,
                              void* d_out, int out_size, void* d_ws, size_t ws_size,
                              hipStream_t stream) {
    const int* adj            = (const int*)d_in[0];
    const int* exercise_data  = (const int*)d_in[2];
    const int* respond        = (const int*)d_in[3];
    const float* target       = (const float*)d_in[4];
    const float* ex_embed     = (const float*)d_in[5];
    const float* kc_embed     = (const float*)d_in[6];
    const float* W1           = (const float*)d_in[7];
    const float* a_att        = (const float*)d_in[8];
    const float* E            = (const float*)d_in[9];
    const float* rd_w         = (const float*)d_in[10];
    const float* rd_b         = (const float*)d_in[11];
    const float* w_ih         = (const float*)d_in[12];
    const float* w_hh         = (const float*)d_in[13];
    const float* b_ih         = (const float*)d_in[14];
    const float* b_hh         = (const float*)d_in[15];
    const float* fc1_w        = (const float*)d_in[16];
    const float* fc1_b        = (const float*)d_in[17];
    const float* fc2_w        = (const float*)d_in[18];
    const float* fc2_b        = (const float*)d_in[19];
    float* out = (float*)d_out;

    float* ws = (float*)d_ws;
    size_t off = 0;
    auto alloc = [&](size_t n) { float* p = ws + off; off += (n + 3) & ~(size_t)3; return p; };
    float* kcWhT   = alloc(2 * 128 * 500);
    float* s_kc    = alloc(1000);
    float* v1      = alloc(256);
    float* s_ex    = alloc(2 * N_EX);
    float* emb_e   = alloc((size_t)N_EX * 128);
    float* rd_wT   = alloc(2 * 256 * 128);
    float* w_ihT0  = alloc(128 * 512);
    float* w_ihT1  = alloc(128 * 512);
    float* fc1_AT  = alloc(128 * 128);
    float* fc1_BT  = alloc(128 * 128);
    float* wlstm   = alloc(32768);     // 65536 f16
    float* new_kc  = alloc((size_t)2 * N_EX * 128);
    float* projC   = alloc((size_t)(2 * N_EX + 1) * 512);
    float* assessP = alloc((size_t)N_EX * 128);
    float* learn16 = alloc((size_t)BB * 499 * 64);   // f16
    float* loss_accum = alloc(4);

    k_precomp<<<256, 256, 0, stream>>>(rd_w, w_ih, fc1_w, b_ih, b_hh, W1, a_att, w_hh,
                                       rd_wT, w_ihT0, w_ihT1, fc1_AT, fc1_BT, v1,
                                       (unsigned short*)wlstm, projC);
    k_kc<<<dim3(500, 2), 128, 0, stream>>>(kc_embed, W1, a_att, kcWhT, s_kc);
    k_sex<<<79, 256, 0, stream>>>(ex_embed, v1, s_ex);
    k_attnk<<<N_EX / 8, 256, 0, stream>>>(adj, s_ex, s_kc, kcWhT, new_kc);
    k_gat2m<<<N_EX / 8, 256, 0, stream>>>(new_kc, ex_embed, E, rd_wT, rd_b, emb_e);
    k_proj<<<N_EX / 16, 512, 0, stream>>>(emb_e, w_ihT0, w_ihT1, fc1_BT, b_ih, b_hh,
                                          projC, assessP);
    hipMemsetAsync(loss_accum, 0, sizeof(float), stream);
    k_lstm<<<BB, 512, 0, stream>>>((const uint4*)wlstm, projC, respond,
                                   (unsigned short*)learn16);
    k_mlp<<<NROWS / 64, 256, 0, stream>>>((const unsigned short*)learn16, assessP, fc1_AT,
                                          fc1_b, fc2_w, fc2_b,
                                          exercise_data, target, out, loss_accum);
    k_final<<<1, 1, 0, stream>>>(loss_accum, out);
}

// Round 12
// 697.168 us; speedup vs baseline: 1.1755x; 1.1485x over previous
//
#include <hip/hip_runtime.h>
#include <math.h>

#define N_EX 10000
#define N_KC 500
#define D 128
#define HID 128
#define BB 256
#define SS 500
#define NROWS 127744   // B*(S-1)

typedef float vf4 __attribute__((ext_vector_type(4)));
typedef _Float16 hf2 __attribute__((ext_vector_type(2)));
typedef _Float16 hf8 __attribute__((ext_vector_type(8)));
typedef float f32x4 __attribute__((ext_vector_type(4)));

__device__ __forceinline__ float sigm(float x) { return 1.f / (1.f + __expf(-x)); }
__device__ __forceinline__ float tanh_fast(float x) { return 1.f - 2.f / (1.f + __expf(2.f * x)); }

__device__ __forceinline__ hf2 u2h(unsigned v) { union { unsigned u; hf2 h; } x; x.u = v; return x.h; }

// quad-lane sum via DPP quad_perm (VALU pipe, no LDS)
__device__ __forceinline__ float quad_sum(float x) {
    int a = __builtin_amdgcn_update_dpp(0, __float_as_int(x), 0xB1, 0xF, 0xF, true); // xor 1
    x += __int_as_float(a);
    int b = __builtin_amdgcn_update_dpp(0, __float_as_int(x), 0x4E, 0xF, 0xF, true); // xor 2
    x += __int_as_float(b);
    return x;
}

// ---------------- precompute ----------------
// w_all16 [1152 x 128] f16, row n -> output col n:
//   n in [0,512):    projC col c=n (u-major interleave c=u*4+gate): w_ih[(c&3)*128+(c>>2)][128+k]
//   n in [512,1024): c=n-512: w_ih[(c&3)*128+(c>>2)][k]
//   n in [1024,1152): j=n-1024: fc1_w[j][128+k]   (assessP)
// gb512[c] = b_ih[(c&3)*128+(c>>2)] + b_hh[..]; projC row0 = gb512 (respond==0).
// fc1A16[j][k] = fc1_w[j][k] f16. wlstm16 layout unchanged (R8).
__global__ void k_precomp(const float* rd_w, const float* w_ih, const float* fc1_w,
                          const float* b_ih, const float* b_hh, const float* W1, const float* a_att,
                          const float* w_hh,
                          float* rd_wT, unsigned short* w_all16, unsigned short* fc1A16,
                          float* gb512, float* v1,
                          unsigned short* wlstm16, float* projC) {
    int idx = blockIdx.x * blockDim.x + threadIdx.x;
    int stride = gridDim.x * blockDim.x;
    const int N1 = 2 * 256 * 128;     // rd_wT
    const int NW = 1152 * 128;        // w_all16
    const int NF = 128 * 128;         // fc1A16
    const int NG = 512;               // gb512 + projC row0
    const int N7 = 256;               // v1
    const int N8 = 65536;             // wlstm16
    int total = N1 + NW + NF + NG + N7 + N8;
    for (int tt = idx; tt < total; tt += stride) {
        int u = tt;
        if (u < N1) {
            int h = u / (256 * 128); int rem = u % (256 * 128); int c = rem / 128; int dd = rem % 128;
            rd_wT[u] = rd_w[h * 128 * 256 + dd * 256 + c];
        } else if ((u -= N1) < NW) {
            int n = u >> 7, k = u & 127;
            float val;
            if (n < 512) {
                int c = n; val = w_ih[((c & 3) * 128 + (c >> 2)) * 256 + 128 + k];
            } else if (n < 1024) {
                int c = n - 512; val = w_ih[((c & 3) * 128 + (c >> 2)) * 256 + k];
            } else {
                int j = n - 1024; val = fc1_w[j * 256 + 128 + k];
            }
            ((_Float16*)w_all16)[u] = (_Float16)val;
        } else if ((u -= NW) < NF) {
            int j = u >> 7, k = u & 127;
            ((_Float16*)fc1A16)[u] = (_Float16)fc1_w[j * 256 + k];
        } else if ((u -= NF) < NG) {
            int c = u;
            float v = b_ih[(c & 3) * 128 + (c >> 2)] + b_hh[(c & 3) * 128 + (c >> 2)];
            gb512[c] = v;
            projC[c] = v;
        } else if ((u -= NG) < N7) {
            int h = u / 128, k = u % 128;
            const float* wr = W1 + h * 16384 + k * 128;
            const float* av = a_att + h * 256;
            float acc = 0.f;
            for (int d = 0; d < 128; ++d) acc += wr[d] * av[d];
            v1[u] = acc;
        } else {
            u -= N7;
            int x = u & 7;
            int t = (u >> 3) & 511;
            int i = u >> 12;
            int g = i >> 2, j = i & 3;
            int uu = t >> 2, q = t & 3;
            float val = w_hh[(g * 128 + uu) * 128 + q * 32 + j * 8 + x];
            ((_Float16*)wlstm16)[u] = (_Float16)val;
        }
    }
}

// ---------------- kc_Wh (transposed) + s_kc ----------------
__global__ void k_kc(const float* kc_embed, const float* W1, const float* a_att,
                     float* kcWhT, float* s_kc) {
    int j = blockIdx.x, h = blockIdx.y, d = threadIdx.x;
    __shared__ float row[128];
    __shared__ float red[128];
    row[d] = kc_embed[j * 128 + d];
    __syncthreads();
    const float* w = W1 + h * 16384;
    float acc = 0.f;
    for (int k = 0; k < 128; ++k) acc += row[k] * w[k * 128 + d];
    kcWhT[((size_t)(h * 128 + d)) * 500 + j] = acc;
    red[d] = acc * a_att[h * 256 + 128 + d];
    __syncthreads();
    for (int s = 64; s > 0; s >>= 1) { if (d < s) red[d] += red[d + s]; __syncthreads(); }
    if (d == 0) s_kc[h * 500 + j] = red[0];
}

// ---------------- s_ex[h][i] = ex_embed[i] . v1[h] ----------------
__global__ void k_sex(const float* ex_embed, const float* v1, float* s_ex) {
    int t = blockIdx.x * blockDim.x + threadIdx.x;
    if (t >= 2 * N_EX) return;
    int h = t / N_EX, i = t % N_EX;
    const float4* e4 = (const float4*)(ex_embed + (size_t)i * 128);
    const float4* v4 = (const float4*)(v1 + h * 128);
    float acc = 0.f;
    for (int k = 0; k < 32; ++k) {
        float4 a = e4[k], b = v4[k];
        acc += a.x * b.x + a.y * b.y + a.z * b.z + a.w * b.w;
    }
    s_ex[h * N_EX + i] = acc;
}

// ---------------- fused attention softmax + new_kc GEMV, BOTH heads / block ----------------
__global__ __launch_bounds__(256) void k_attnk(const int* adj, const float* s_ex, const float* s_kc,
                                               const float* kcWhT, float* new_kc) {
    int i0 = blockIdx.x * 8, t = threadIdx.x;
    __shared__ vf4 at4[2][1500];
    __shared__ float skc_l[2][500];
    float* at0 = (float*)at4[0];
    float* at1 = (float*)at4[1];
    for (int j = t; j < 1000; j += 256) ((float*)skc_l)[j] = s_kc[j];
    __syncthreads();
    {
        int lg = t >> 5, lane = t & 31;
        int i = i0 + lg;
        float sex0 = s_ex[i];
        float sex1 = s_ex[N_EX + i];
        const int* arow = adj + (size_t)i * 500;
        float lmax0 = -INFINITY, lmax1 = -INFINITY;
        for (int j = lane; j < 500; j += 32) {
            bool m = arow[j] > 0;
            float e0 = sex0 + skc_l[0][j];
            e0 = (e0 >= 0.f) ? e0 : 0.2f * e0;
            e0 = m ? e0 : -INFINITY;
            float e1 = sex1 + skc_l[1][j];
            e1 = (e1 >= 0.f) ? e1 : 0.2f * e1;
            e1 = m ? e1 : -INFINITY;
            at0[j * 12 + lg] = e0;
            at1[j * 12 + lg] = e1;
            lmax0 = fmaxf(lmax0, e0);
            lmax1 = fmaxf(lmax1, e1);
        }
#pragma unroll
        for (int m = 16; m > 0; m >>= 1) {
            lmax0 = fmaxf(lmax0, __shfl_xor(lmax0, m));
            lmax1 = fmaxf(lmax1, __shfl_xor(lmax1, m));
        }
        float lsum0 = 0.f, lsum1 = 0.f;
        for (int j = lane; j < 500; j += 32) {
            float w0 = __expf(at0[j * 12 + lg] - lmax0);
            float w1 = __expf(at1[j * 12 + lg] - lmax1);
            at0[j * 12 + lg] = w0;
            at1[j * 12 + lg] = w1;
            lsum0 += w0; lsum1 += w1;
        }
#pragma unroll
        for (int m = 16; m > 0; m >>= 1) {
            lsum0 += __shfl_xor(lsum0, m);
            lsum1 += __shfl_xor(lsum1, m);
        }
        float inv0 = 1.f / lsum0, inv1 = 1.f / lsum1;
        for (int j = lane; j < 500; j += 32) {
            at0[j * 12 + lg] *= inv0;
            at1[j * 12 + lg] *= inv1;
        }
    }
    __syncthreads();
    int d = t & 127, half = t >> 7;
    for (int h = 0; h < 2; ++h) {
        const float* at = (h == 0) ? at0 : at1;
        const float* kcwd = kcWhT + ((size_t)(h * 128 + d)) * 500;
        vf4 acc = {0.f, 0.f, 0.f, 0.f};
        for (int j4 = 0; j4 < 125; ++j4) {
            vf4 w = *(const vf4*)(kcwd + j4 * 4);
            vf4 a0 = *(const vf4*)(at + (j4 * 4 + 0) * 12 + half * 4);
            vf4 a1 = *(const vf4*)(at + (j4 * 4 + 1) * 12 + half * 4);
            vf4 a2 = *(const vf4*)(at + (j4 * 4 + 2) * 12 + half * 4);
            vf4 a3 = *(const vf4*)(at + (j4 * 4 + 3) * 12 + half * 4);
            acc += a0 * w.x + a1 * w.y + a2 * w.z + a3 * w.w;
        }
        new_kc[((size_t)h * N_EX + i0 + half * 4 + 0) * 128 + d] = acc.x;
        new_kc[((size_t)h * N_EX + i0 + half * 4 + 1) * 128 + d] = acc.y;
        new_kc[((size_t)h * N_EX + i0 + half * 4 + 2) * 128 + d] = acc.z;
        new_kc[((size_t)h * N_EX + i0 + half * 4 + 3) * 128 + d] = acc.w;
    }
}

// ---------------- fused GAT tail + merge -> emb16 (f16)  (8 rows / block) ----------------
__global__ __launch_bounds__(256) void k_gat2m(const float* new_kc, const float* ex_embed,
                                               const float* E, const float* rd_wT,
                                               const float* rd_b, _Float16* emb16) {
    int i0 = blockIdx.x * 8, t = threadIdx.x;
    int d = t & 127, half = t >> 7;
    __shared__ float exrT[128 * 8];
    __shared__ float nkT[2][128 * 8];
    __shared__ float prT[128 * 8];
    __shared__ float Hl[2][8 * 128];
    for (int idx = t; idx < 8 * 128; idx += 256) {
        int r = idx >> 7, k = idx & 127;
        exrT[k * 8 + r]   = ex_embed[(size_t)i0 * 128 + idx];
        nkT[0][k * 8 + r] = new_kc[((size_t)i0) * 128 + idx];
        nkT[1][k * 8 + r] = new_kc[((size_t)N_EX + i0) * 128 + idx];
    }
    __syncthreads();
    for (int h = 0; h < 2; ++h) {
        const float* Eh = E + h * 16384;
        const float* rt = rd_wT + h * 256 * 128;
        float rb = rd_b[h * 128 + d];
        vf4 acc2 = {0.f, 0.f, 0.f, 0.f};
        for (int k = 0; k < 128; ++k) {
            float ev = Eh[k * 128 + d];
            vf4 ex4 = *(const vf4*)(exrT + k * 8 + half * 4);
            acc2 += ex4 * ev;
        }
        {
            vf4 nk4 = *(const vf4*)(nkT[h] + d * 8 + half * 4);
            *(vf4*)(prT + d * 8 + half * 4) = nk4 * acc2;
        }
        __syncthreads();
        vf4 acc3 = {0.f, 0.f, 0.f, 0.f};
        for (int c = 0; c < 128; ++c) {
            float w = rt[c * 128 + d];
            vf4 nk4 = *(const vf4*)(nkT[h] + c * 8 + half * 4);
            acc3 += nk4 * w;
        }
        for (int c = 0; c < 128; ++c) {
            float w = rt[(128 + c) * 128 + d];
            vf4 pr4 = *(const vf4*)(prT + c * 8 + half * 4);
            acc3 += pr4 * w;
        }
#pragma unroll
        for (int r = 0; r < 4; ++r) {
            float v = ((r == 0) ? acc3.x : (r == 1) ? acc3.y : (r == 2) ? acc3.z : acc3.w) + rb;
            v = (v > 0.f) ? v : expm1f(v);
            Hl[h][(half * 4 + r) * 128 + d] = v;
        }
        __syncthreads();
    }
    for (int idx = t; idx < 8 * 128; idx += 256) {
        int r = idx >> 7, dd = idx & 127;
        int hs = dd >> 6;
        int c0 = (2 * dd) & 127, c1 = (2 * dd + 1) & 127;
        emb16[((size_t)i0 + r) * 128 + dd] =
            (_Float16)(0.5f * (Hl[hs][r * 128 + c0] + Hl[hs][r * 128 + c1]));
    }
}

// ---------------- MFMA proj: C[10000 x 1152] = emb16 @ w_all16^T ----------------
// 64x64 tiles; grid (157, 18). nt<8 -> projC resp-1 block (+bias); nt<16 -> resp-0 block (+bias);
// nt>=16 -> assessP. w_all16 row order makes output cols land directly in projC's u-major layout.
__global__ __launch_bounds__(256) void k_projM(const unsigned short* __restrict__ emb16,
                                               const unsigned short* __restrict__ w_all16,
                                               const float* __restrict__ gb512,
                                               float* __restrict__ projC,
                                               float* __restrict__ assessP) {
    int mt = blockIdx.x, nt = blockIdx.y;
    int i0 = mt * 64, n0 = nt * 64;
    int t = threadIdx.x;
    __shared__ _Float16 Al[64 * 136];
    __shared__ _Float16 Bl[64 * 136];
    for (int idx = t; idx < 512; idx += 256) {
        int r = idx >> 3, sg = idx & 7;
        int gi = i0 + r; if (gi >= N_EX) gi = N_EX - 1;
        *(uint4*)(Al + r * 136 + sg * 8) = *(const uint4*)(emb16 + (size_t)gi * 128 + sg * 8);
    }
    for (int idx = t; idx < 512; idx += 256) {
        int r = idx >> 3, sg = idx & 7;
        *(uint4*)(Bl + r * 136 + sg * 8) = *(const uint4*)(w_all16 + (size_t)(n0 + r) * 128 + sg * 8);
    }
    __syncthreads();
    int w = t >> 6, l = t & 63, quad = l >> 4, lx = l & 15;
    const _Float16* ab = Al + ((w << 4) + lx) * 136 + (quad << 3);
    hf8 a0 = *(const hf8*)(ab);
    hf8 a1 = *(const hf8*)(ab + 32);
    hf8 a2 = *(const hf8*)(ab + 64);
    hf8 a3 = *(const hf8*)(ab + 96);
    f32x4 acc[4];
#pragma unroll
    for (int ct = 0; ct < 4; ++ct) {
        const _Float16* bb = Bl + ((ct << 4) + lx) * 136 + (quad << 3);
        f32x4 c = {0.f, 0.f, 0.f, 0.f};
        c = __builtin_amdgcn_mfma_f32_16x16x32_f16(a0, *(const hf8*)(bb),      c, 0, 0, 0);
        c = __builtin_amdgcn_mfma_f32_16x16x32_f16(a1, *(const hf8*)(bb + 32), c, 0, 0, 0);
        c = __builtin_amdgcn_mfma_f32_16x16x32_f16(a2, *(const hf8*)(bb + 64), c, 0, 0, 0);
        c = __builtin_amdgcn_mfma_f32_16x16x32_f16(a3, *(const hf8*)(bb + 96), c, 0, 0, 0);
        acc[ct] = c;
    }
    int rbase = i0 + (w << 4) + (quad << 2);
    if (nt < 16) {
        size_t rowbase = (nt < 8) ? 1 : (size_t)(1 + N_EX);
        int cc = n0 & 511;
#pragma unroll
        for (int ct = 0; ct < 4; ++ct) {
            int col = cc + (ct << 4) + lx;
            float gb = gb512[col];
#pragma unroll
            for (int reg = 0; reg < 4; ++reg) {
                int gi = rbase + reg;
                if (gi < N_EX) projC[(rowbase + gi) * 512 + col] = acc[ct][reg] + gb;
            }
        }
    } else {
        int cc = n0 - 1024;
#pragma unroll
        for (int ct = 0; ct < 4; ++ct) {
            int col = cc + (ct << 4) + lx;
#pragma unroll
            for (int reg = 0; reg < 4; ++reg) {
                int gi = rbase + reg;
                if (gi < N_EX) assessP[(size_t)gi * 128 + col] = acc[ct][reg];
            }
        }
    }
}

// ---------------- persistent LSTM (R10 engine: b128 u-major gather, f16 weights, learn f16) ----------------
__global__ __launch_bounds__(512, 2) void k_lstm(const uint4* __restrict__ w16,
                                                 const float* __restrict__ projC,
                                                 const int* __restrict__ respond,
                                                 unsigned short* __restrict__ learn16) {
    int b = blockIdx.x, t = threadIdx.x;
    int u = t >> 2, q = t & 3;
    __shared__ uint4 hbuf4[2][18];
    __shared__ int rrow[500];
    uint4 w[16];
#pragma unroll
    for (int i = 0; i < 16; ++i) w[i] = w16[i * 512 + t];
    for (int s = t; s < 500; s += 512) rrow[s] = respond[b * 500 + s];
    if (t < 36) { uint4 z = {0u, 0u, 0u, 0u}; ((uint4*)hbuf4)[t] = z; }
    float c = 0.f;
    __syncthreads();
    vf4 xg_n = ((const vf4*)(projC + (size_t)rrow[0] * 512))[u];
    for (int s = 0; s < 500; ++s) {
        int par = s & 1;
        vf4 xg = xg_n;
        if (s < 499) xg_n = ((const vf4*)(projC + (size_t)rrow[s + 1] * 512))[u];
        const uint4* hsegp = (const uint4*)((const unsigned short*)hbuf4[par] + q * 32);
        uint4 h4[4];
#pragma unroll
        for (int j = 0; j < 4; ++j) h4[j] = hsegp[j];
        float p0 = 0.f, p1 = 0.f, p2 = 0.f, p3 = 0.f;
#pragma unroll
        for (int j = 0; j < 4; ++j) {
            hf2 ha = u2h(h4[j].x), hb = u2h(h4[j].y), hc = u2h(h4[j].z), hd = u2h(h4[j].w);
            uint4 w0 = w[j], w1 = w[4 + j], w2 = w[8 + j], w3 = w[12 + j];
            p0 = __builtin_amdgcn_fdot2(u2h(w0.x), ha, p0, false);
            p0 = __builtin_amdgcn_fdot2(u2h(w0.y), hb, p0, false);
            p0 = __builtin_amdgcn_fdot2(u2h(w0.z), hc, p0, false);
            p0 = __builtin_amdgcn_fdot2(u2h(w0.w), hd, p0, false);
            p1 = __builtin_amdgcn_fdot2(u2h(w1.x), ha, p1, false);
            p1 = __builtin_amdgcn_fdot2(u2h(w1.y), hb, p1, false);
            p1 = __builtin_amdgcn_fdot2(u2h(w1.z), hc, p1, false);
            p1 = __builtin_amdgcn_fdot2(u2h(w1.w), hd, p1, false);
            p2 = __builtin_amdgcn_fdot2(u2h(w2.x), ha, p2, false);
            p2 = __builtin_amdgcn_fdot2(u2h(w2.y), hb, p2, false);
            p2 = __builtin_amdgcn_fdot2(u2h(w2.z), hc, p2, false);
            p2 = __builtin_amdgcn_fdot2(u2h(w2.w), hd, p2, false);
            p3 = __builtin_amdgcn_fdot2(u2h(w3.x), ha, p3, false);
            p3 = __builtin_amdgcn_fdot2(u2h(w3.y), hb, p3, false);
            p3 = __builtin_amdgcn_fdot2(u2h(w3.z), hc, p3, false);
            p3 = __builtin_amdgcn_fdot2(u2h(w3.w), hd, p3, false);
        }
        float gi = quad_sum(p0) + xg.x;
        float gf = quad_sum(p1) + xg.y;
        float gG = quad_sum(p2) + xg.z;
        float go = quad_sum(p3) + xg.w;
        float ii = sigm(gi), ff = sigm(gf), tg = tanh_fast(gG), oo = sigm(go);
        c = ff * c + ii * tg;
        float hh = oo * tanh_fast(c);
        if (q == 0) {
            union { unsigned short us; _Float16 hf; } cv; cv.hf = (_Float16)hh;
            ((unsigned short*)hbuf4[par ^ 1])[u] = cv.us;
            if (s < 499) learn16[((size_t)b * 499 + s) * 128 + u] = cv.us;
        }
        __syncthreads();
    }
}

// ---------------- MFMA MLP head: y=relu(learn@fc1_A^T + aP + b1); pred=y.fc2+b2; loss ----------------
__global__ __launch_bounds__(256) void k_mlpM(const unsigned short* __restrict__ learn16,
                                              const unsigned short* __restrict__ fc1A16,
                                              const float* __restrict__ assessP,
                                              const float* __restrict__ fc1_b,
                                              const float* __restrict__ fc2_w,
                                              const float* __restrict__ fc2_b,
                                              const int* __restrict__ exercise_data,
                                              const float* __restrict__ target,
                                              float* __restrict__ out,
                                              float* __restrict__ loss_accum) {
    int tile = blockIdx.x;
    int row0 = tile * 64;
    int t = threadIdx.x;
    __shared__ _Float16 Al[64 * 136];
    __shared__ _Float16 Bl[128 * 136];
    __shared__ float red[4];
    for (int idx = t; idx < 512; idx += 256) {
        int r = idx >> 3, sg = idx & 7;
        *(uint4*)(Al + r * 136 + sg * 8) = *(const uint4*)(learn16 + ((size_t)row0 + r) * 128 + sg * 8);
    }
    for (int idx = t; idx < 1024; idx += 256) {
        int r = idx >> 3, sg = idx & 7;
        *(uint4*)(Bl + r * 136 + sg * 8) = *(const uint4*)(fc1A16 + r * 128 + sg * 8);
    }
    __syncthreads();
    int w = t >> 6, l = t & 63, quad = l >> 4, lx = l & 15;
    const _Float16* ab = Al + ((w << 4) + lx) * 136 + (quad << 3);
    hf8 a0 = *(const hf8*)(ab);
    hf8 a1 = *(const hf8*)(ab + 32);
    hf8 a2 = *(const hf8*)(ab + 64);
    hf8 a3 = *(const hf8*)(ab + 96);
    f32x4 acc[8];
#pragma unroll
    for (int ct = 0; ct < 8; ++ct) {
        const _Float16* bb = Bl + ((ct << 4) + lx) * 136 + (quad << 3);
        f32x4 c = {0.f, 0.f, 0.f, 0.f};
        c = __builtin_amdgcn_mfma_f32_16x16x32_f16(a0, *(const hf8*)(bb),      c, 0, 0, 0);
        c = __builtin_amdgcn_mfma_f32_16x16x32_f16(a1, *(const hf8*)(bb + 32), c, 0, 0, 0);
        c = __builtin_amdgcn_mfma_f32_16x16x32_f16(a2, *(const hf8*)(bb + 64), c, 0, 0, 0);
        c = __builtin_amdgcn_mfma_f32_16x16x32_f16(a3, *(const hf8*)(bb + 96), c, 0, 0, 0);
        acc[ct] = c;
    }
    int eidx[4];
#pragma unroll
    for (int reg = 0; reg < 4; ++reg) {
        int n = row0 + (w << 4) + (quad << 2) + reg;
        int b = n / 499, sidx = n - b * 499;
        eidx[reg] = exercise_data[b * 500 + sidx + 1];
    }
    float rs[4] = {0.f, 0.f, 0.f, 0.f};
#pragma unroll
    for (int ct = 0; ct < 8; ++ct) {
        int col = (ct << 4) + lx;
        float b1v = fc1_b[col], f2v = fc2_w[col];
#pragma unroll
        for (int reg = 0; reg < 4; ++reg) {
            float aP = (eidx[reg] > 0) ? assessP[(size_t)(eidx[reg] - 1) * 128 + col] : 0.f;
            float y = acc[ct][reg] + aP + b1v;
            y = y > 0.f ? y : 0.f;
            rs[reg] += y * f2v;
        }
    }
#pragma unroll
    for (int reg = 0; reg < 4; ++reg) {
        float s = rs[reg];
        s += __shfl_xor(s, 1); s += __shfl_xor(s, 2); s += __shfl_xor(s, 4); s += __shfl_xor(s, 8);
        rs[reg] = s;
    }
    float fb2 = fc2_b[0];
    float lloss = 0.f;
    if (lx == 0) {
#pragma unroll
        for (int reg = 0; reg < 4; ++reg) {
            int n = row0 + (w << 4) + (quad << 2) + reg;
            float p = rs[reg] + fb2;
            float tg = target[n];
            out[1 + n] = 1.f / (1.f + expf(-p));
            float ab2 = fabsf(p);
            lloss += fmaxf(p, 0.f) - p * tg + log1pf(expf(-ab2));
            out[1 + NROWS + n] = tg;
        }
    }
    lloss += __shfl_xor(lloss, 16);
    lloss += __shfl_xor(lloss, 32);
    if (l == 0) red[w] = lloss;
    __syncthreads();
    if (t == 0) atomicAdd(loss_accum, red[0] + red[1] + red[2] + red[3]);
}

__global__ void k_final(const float* loss_accum, float* out) {
    out[0] = loss_accum[0] * (1.f / (float)NROWS);
}

extern "C" void kernel_launch(void* const* d_in, const int* in_sizes, int n_in,
                              void* d_out, int out_size, void* d_ws, size_t ws_size,
                              hipStream_t stream) {
    const int* adj            = (const int*)d_in[0];
    const int* exercise_data  = (const int*)d_in[2];
    const int* respond        = (const int*)d_in[3];
    const float* target       = (const float*)d_in[4];
    const float* ex_embed     = (const float*)d_in[5];
    const float* kc_embed     = (const float*)d_in[6];
    const float* W1           = (const float*)d_in[7];
    const float* a_att        = (const float*)d_in[8];
    const float* E            = (const float*)d_in[9];
    const float* rd_w         = (const float*)d_in[10];
    const float* rd_b         = (const float*)d_in[11];
    const float* w_ih         = (const float*)d_in[12];
    const float* w_hh         = (const float*)d_in[13];
    const float* b_ih         = (const float*)d_in[14];
    const float* b_hh         = (const float*)d_in[15];
    const float* fc1_w        = (const float*)d_in[16];
    const float* fc1_b        = (const float*)d_in[17];
    const float* fc2_w        = (const float*)d_in[18];
    const float* fc2_b        = (const float*)d_in[19];
    float* out = (float*)d_out;

    float* ws = (float*)d_ws;
    size_t off = 0;
    auto alloc = [&](size_t n) { float* p = ws + off; off += (n + 3) & ~(size_t)3; return p; };
    float* kcWhT   = alloc(2 * 128 * 500);
    float* s_kc    = alloc(1000);
    float* v1      = alloc(256);
    float* s_ex    = alloc(2 * N_EX);
    float* rd_wT   = alloc(2 * 256 * 128);
    float* wlstm   = alloc(32768);                    // 65536 f16
    float* w_all16 = alloc(1152 * 64);                // 147456 f16
    float* fc1A16  = alloc(8192);                     // 16384 f16
    float* gb512   = alloc(512);
    float* emb16   = alloc((size_t)N_EX * 64);        // 10000*128 f16
    float* new_kc  = alloc((size_t)2 * N_EX * 128);
    float* projC   = alloc((size_t)(2 * N_EX + 1) * 512);
    float* assessP = alloc((size_t)N_EX * 128);
    float* learn16 = alloc((size_t)BB * 499 * 64);    // f16
    float* loss_accum = alloc(4);

    k_precomp<<<256, 256, 0, stream>>>(rd_w, w_ih, fc1_w, b_ih, b_hh, W1, a_att, w_hh,
                                       rd_wT, (unsigned short*)w_all16, (unsigned short*)fc1A16,
                                       gb512, v1, (unsigned short*)wlstm, projC);
    k_kc<<<dim3(500, 2), 128, 0, stream>>>(kc_embed, W1, a_att, kcWhT, s_kc);
    k_sex<<<79, 256, 0, stream>>>(ex_embed, v1, s_ex);
    k_attnk<<<N_EX / 8, 256, 0, stream>>>(adj, s_ex, s_kc, kcWhT, new_kc);
    k_gat2m<<<N_EX / 8, 256, 0, stream>>>(new_kc, ex_embed, E, rd_wT, rd_b, (_Float16*)emb16);
    k_projM<<<dim3(157, 18), 256, 0, stream>>>((const unsigned short*)emb16,
                                               (const unsigned short*)w_all16, gb512,
                                               projC, assessP);
    hipMemsetAsync(loss_accum, 0, sizeof(float), stream);
    k_lstm<<<BB, 512, 0, stream>>>((const uint4*)wlstm, projC, respond,
                                   (unsigned short*)learn16);
    k_mlpM<<<NROWS / 64, 256, 0, stream>>>((const unsigned short*)learn16,
                                           (const unsigned short*)fc1A16, assessP,
                                           fc1_b, fc2_w, fc2_b,
                                           exercise_data, target, out, loss_accum);
    k_final<<<1, 1, 0, stream>>>(loss_accum, out);
}